// Round 4
// baseline (825.845 us; speedup 1.0000x reference)
//
#include <hip/hip_runtime.h>

#define DEV __device__ __forceinline__

DEV float mask_val(const unsigned char* mb, int n) {
  // Detect train_mask storage from its first element: uint8 bool / int32 / float32.
  unsigned b0 = mb[0], b1 = mb[1], b2 = mb[2], b3 = mb[3];
  if (b0 <= 1u && b1 == b0 && b2 == b0 && b3 == b0) {
    return mb[n] ? 1.f : 0.f;                       // 1-byte bool
  } else if (b1 == 0u && b2 == 0u && b3 == 0u) {
    return ((const int*)mb)[n] ? 1.f : 0.f;         // int32
  } else {
    return (((const float*)mb)[n] != 0.f) ? 1.f : 0.f; // float32
  }
}

// ---------------- K0: rank-1 collapses of the context-attention algebra ----------------
__global__ void k_precompute(const float* __restrict__ tf_w, const float* __restrict__ tf_b,
                             const float* __restrict__ deg_w, const float* __restrict__ deg_b,
                             const float* __restrict__ wenc_w, const float* __restrict__ wenc_b,
                             const float* __restrict__ comb_w, float* __restrict__ cbuf) {
  int c = threadIdx.x;  // 64 threads
  float A0 = 0, B0 = 0, A1 = 0, B1 = 0, P0 = 0, Q0 = 0, P1 = 0, Q1 = 0;
  for (int j = 0; j < 64; ++j) {
    float w  = wenc_w[j * 64 + c];
    float cw = comb_w[(64 + j) * 64 + c];
    float twj = tf_w[j], tbj = tf_b[j], dwj = deg_w[j], dbj = deg_b[j];
    A0 += twj * w;  B0 += tbj * w;
    A1 += dwj * w;  B1 += dbj * w;
    P0 += twj * cw; Q0 += tbj * cw;
    P1 += dwj * cw; Q1 += dbj * cw;
  }
  float wb = wenc_b[c];
  cbuf[c]       = A0; cbuf[64 + c]  = B0 + wb;
  cbuf[128 + c] = A1; cbuf[192 + c] = B1 + wb;
  cbuf[256 + c] = P0; cbuf[320 + c] = Q0;
  cbuf[384 + c] = P1; cbuf[448 + c] = Q1;
}

// ---------------- K1: h = relu(x@lin); q, k'=k+be, v'=v+be, skip ----------------
DEV float dot64_bcast(const float4* __restrict__ row, const float* __restrict__ w, float acc) {
#pragma unroll
  for (int j4 = 0; j4 < 16; ++j4) {
    float4 hv = row[j4];
    acc = fmaf(hv.x, w[4 * j4 + 0], acc);
    acc = fmaf(hv.y, w[4 * j4 + 1], acc);
    acc = fmaf(hv.z, w[4 * j4 + 2], acc);
    acc = fmaf(hv.w, w[4 * j4 + 3], acc);
  }
  return acc;
}

__global__ __launch_bounds__(256) void k_node_proj(
    const float* __restrict__ x,
    const float* __restrict__ lin_w, const float* __restrict__ lin_b,
    const float* __restrict__ Wq, const float* __restrict__ bq,
    const float* __restrict__ Wk, const float* __restrict__ bk,
    const float* __restrict__ Wv, const float* __restrict__ bv,
    const float* __restrict__ Wsk, const float* __restrict__ bsk,
    const float* __restrict__ be,
    float* __restrict__ q, float* __restrict__ k, float* __restrict__ v,
    float* __restrict__ skipout, int N) {
  __shared__ float xs[4096];
  __shared__ float hs[4096];
  const int tid = threadIdx.x;
  const int c = tid & 63;
  const int rr0 = tid >> 6;
  const float bec = be[c];
  const int ntiles = (N + 63) >> 6;
  for (int tile = blockIdx.x; tile < ntiles; tile += gridDim.x) {
    const int base = tile << 6;
    for (int idx = tid; idx < 4096; idx += 256) {
      int n = base + (idx >> 6);
      xs[idx] = (n < N) ? x[(size_t)n * 64 + (idx & 63)] : 0.f;
    }
    __syncthreads();
    {
      float w[64];
#pragma unroll
      for (int j = 0; j < 64; ++j) w[j] = lin_w[j * 64 + c];
      const float bias = lin_b[c];
      for (int r = rr0; r < 64; r += 4) {
        float acc = dot64_bcast((const float4*)&xs[r << 6], w, bias);
        hs[(r << 6) + c] = fmaxf(acc, 0.f);
      }
    }
    __syncthreads();
    const float* Wm[4] = {Wq, Wk, Wv, Wsk};
    const float* bm[4] = {bq, bk, bv, bsk};
    float* om[4] = {q, k, v, skipout};
#pragma unroll 1
    for (int mm = 0; mm < 4; ++mm) {
      float w[64];
#pragma unroll
      for (int j = 0; j < 64; ++j) w[j] = Wm[mm][j * 64 + c];
      const float bias = bm[mm][c] + ((mm == 1 || mm == 2) ? bec : 0.f);
      for (int r = rr0; r < 64; r += 4) {
        const int n = base + r;
        float acc = dot64_bcast((const float4*)&hs[r << 6], w, bias);
        if (n < N) om[mm][(size_t)n * 64 + c] = acc;
      }
    }
    __syncthreads();
  }
}

// ---------------- CSR build ----------------
__global__ __launch_bounds__(256) void k_hist(const int* __restrict__ ei, int* __restrict__ counts, int E) {
  int i = blockIdx.x * 256 + threadIdx.x;
  if (i < E) atomicAdd(&counts[ei[E + i]], 1);
}

__global__ __launch_bounds__(256) void k_scan1(const int* __restrict__ counts, int* __restrict__ excl,
                                               int* __restrict__ bsum, int N) {
  __shared__ int s[256];
  const int t = threadIdx.x;
  const int idx = blockIdx.x * 256 + t;
  int val = (idx < N) ? counts[idx] : 0;
  s[t] = val;
  __syncthreads();
  for (int d = 1; d < 256; d <<= 1) {
    int add = (t >= d) ? s[t - d] : 0;
    __syncthreads();
    s[t] += add;
    __syncthreads();
  }
  if (idx < N) excl[idx] = s[t] - val;
  if (t == 255) bsum[blockIdx.x] = s[255];
}

// parallel exclusive scan of the block sums (B <= 1024 fast path)
__global__ __launch_bounds__(1024) void k_scan2(int* __restrict__ bsum, int B) {
  __shared__ int sm[1024];
  const int t = threadIdx.x;
  if (B <= 1024) {
    int val = (t < B) ? bsum[t] : 0;
    sm[t] = val;
    __syncthreads();
    for (int d = 1; d < 1024; d <<= 1) {
      int add = (t >= d) ? sm[t - d] : 0;
      __syncthreads();
      sm[t] += add;
      __syncthreads();
    }
    if (t < B) bsum[t] = sm[t] - val;  // exclusive
  } else if (t == 0) {
    int acc = 0;
    for (int i = 0; i < B; ++i) { int tt = bsum[i]; bsum[i] = acc; acc += tt; }
  }
}

__global__ __launch_bounds__(256) void k_scan3(const int* __restrict__ bsum, int* __restrict__ rowptr,
                                               int* __restrict__ next, int N, int E) {
  int i = blockIdx.x * 256 + threadIdx.x;
  if (i < N) {
    int r = rowptr[i] + bsum[i >> 8];
    rowptr[i] = r;
    next[i] = r;
  }
  if (i == 0) rowptr[N] = E;
}

__global__ __launch_bounds__(256) void k_fill(const int* __restrict__ ei,
                                              const float* __restrict__ node_time,
                                              const float* __restrict__ edge_time,
                                              int* __restrict__ next, int* __restrict__ srcs,
                                              float* __restrict__ rels, int E) {
  int e = blockIdx.x * 256 + threadIdx.x;
  if (e < E) {
    int s = ei[e], d = ei[E + e];
    int pos = atomicAdd(&next[d], 1);
    srcs[pos] = s;
    rels[pos] = node_time[s] - edge_time[e];
  }
}

// ---------------- K2: CSR gather + online softmax aggregate ----------------
// one wave per dst node; lane = channel; We slices read from padded LDS (no reg arrays);
// depth-3 software pipeline on the random k/v gathers.
__global__ __launch_bounds__(256, 6) void k_aggregate(
    const int* __restrict__ rowptr, const int* __restrict__ srcs, const float* __restrict__ rels,
    const float* __restrict__ q, const float* __restrict__ k, const float* __restrict__ v,
    const float* __restrict__ time_w, const float* __restrict__ time_b,
    const float* __restrict__ We,
    float* __restrict__ h1, int N) {
  __shared__ float swS[4][64];
  __shared__ float We_lds[32 * 65];  // [row j][col c] padded: We_lds[j*65+c] = We[j*64+c]
  const int tid = threadIdx.x;
  const int c = tid & 63;
  const int wv = tid >> 6;
  for (int idx = tid; idx < 32 * 64; idx += 256)
    We_lds[(idx >> 6) * 65 + (idx & 63)] = We[idx];
  __syncthreads();
  const float INV2PI = 0.15915494309189535f;
  const float invs = 0.17677669529663687f;  // 1/sqrt(32)
  const float tw = time_w[c & 31] * INV2PI;
  const float tb = time_b[c & 31] * INV2PI;
  const float* kc = k + c;
  const float* vc = v + c;
  const int h32 = c & 32;     // head offset
  const int r32 = (c & 31) * 65 + h32;  // G-slice base in We_lds
  const int n0 = blockIdx.x * 4 + wv;
  const int nstride = gridDim.x * 4;
  for (int n = n0; n < N; n += nstride) {
    const int start = rowptr[n];
    const int end = rowptr[n + 1];
    const float qc = q[(size_t)n * 64 + c] * invs;
    // G[c] = sum_j q_s[n, h32+j] * We[c&31, h32+j]  (broadcast LDS reads)
    swS[wv][c] = qc;
    float Gc = 0.f;
#pragma unroll
    for (int j = 0; j < 32; ++j) Gc = fmaf(swS[wv][h32 | j], We_lds[r32 + j], Gc);
    float m = -1e30f, den = 0.f, num = 0.f, S = 0.f;
    // depth-3 pipeline: slot0 ready, slot1/slot2 loads in flight
    float r0 = 0.f, r1 = 0.f, r2 = 0.f;
    float kv0 = 0.f, vv0 = 0.f, kv1 = 0.f, vv1 = 0.f, kv2 = 0.f, vv2 = 0.f;
    if (start < end) {
      const int e1 = (start + 1 < end) ? start + 1 : end - 1;
      const int e2 = (start + 2 < end) ? start + 2 : end - 1;
      const int s0 = srcs[start], s1 = srcs[e1], s2 = srcs[e2];
      r0 = rels[start]; r1 = rels[e1]; r2 = rels[e2];
      kv0 = kc[(size_t)s0 * 64]; vv0 = vc[(size_t)s0 * 64];
      kv1 = kc[(size_t)s1 * 64]; vv1 = vc[(size_t)s1 * 64];
      kv2 = kc[(size_t)s2 * 64]; vv2 = vc[(size_t)s2 * 64];
    }
    for (int e = start; e < end; ++e) {
      // compute edge e (slot0)
      float ang = fmaf(r0, tw, tb);
      ang = ang - floorf(ang);
      const float rv = __builtin_amdgcn_cosf(ang);   // cos(2*pi*ang)
      float p = fmaf(rv, Gc, qc * kv0);
#pragma unroll
      for (int msk = 16; msk >= 1; msk >>= 1) p += __shfl_xor(p, msk, 64);
      const float mn = fmaxf(m, p);
      const float sc = __expf(m - mn);
      const float ea = __expf(p - mn);
      num = fmaf(num, sc, ea * vv0);
      S   = fmaf(S, sc, ea * rv);
      den = fmaf(den, sc, ea);
      m = mn;
      // rotate + prefetch edge e+3 (wave-uniform branch)
      r0 = r1; kv0 = kv1; vv0 = vv1;
      r1 = r2; kv1 = kv2; vv1 = vv2;
      if (e + 3 < end) {
        const int sn = srcs[e + 3];
        r2 = rels[e + 3];
        kv2 = kc[(size_t)sn * 64];
        vv2 = vc[(size_t)sn * 64];
      }
    }
    // e-projection contribution: econ[c] = sum_j We[j,c] * S[h32 + j]
    swS[wv][c] = S;
    float econ = 0.f;
#pragma unroll
    for (int j = 0; j < 32; ++j) econ = fmaf(swS[wv][h32 | j], We_lds[j * 65 + c], econ);
    const float agg = (num + econ) / (den + 1e-16f);
    h1[(size_t)n * 64 + c] = agg + h1[(size_t)n * 64 + c];  // + staged skip
  }
}

// ---------------- K4: epilogue (context attention + combine + out + log_softmax) ----------------
__global__ __launch_bounds__(256) void k_epilogue(
    const float* __restrict__ t_int, const float* __restrict__ deg,
    const float* __restrict__ cbuf,
    const float* __restrict__ wx_w, const float* __restrict__ wx_b,
    const float* __restrict__ comb_w, const float* __restrict__ comb_b,
    const float* __restrict__ out_w, const float* __restrict__ out_b,
    const int* __restrict__ y, const unsigned char* __restrict__ maskb,
    float* __restrict__ out, int N) {
  __shared__ float sh[4][64];
  const int tid = threadIdx.x;
  const int c = tid & 63;
  const int wv = tid >> 6;
  float wxreg[64], cbreg[64];
#pragma unroll
  for (int j = 0; j < 64; ++j) { wxreg[j] = wx_w[j * 64 + c]; cbreg[j] = comb_w[j * 64 + c]; }
  const float A0 = cbuf[c], B0 = cbuf[64 + c], A1 = cbuf[128 + c], B1 = cbuf[192 + c];
  const float P0 = cbuf[256 + c], Q0 = cbuf[320 + c], P1 = cbuf[384 + c], Q1 = cbuf[448 + c];
  const float wxb = wx_b[c], cbb = comb_b[c];
  const float ow0 = out_w[c * 2 + 0], ow1 = out_w[c * 2 + 1];
  const float ob0 = out_b[0], ob1 = out_b[1];
  const size_t O1 = (size_t)N * 64;
  const size_t O2 = O1 + (size_t)N * 2;
  const size_t O3 = O2 + (size_t)N;
  const int ngroups = (N + 3) >> 2;
  for (int g = blockIdx.x; g < ngroups; g += gridDim.x) {
    const int n = g * 4 + wv;
    const bool act = n < N;
    float h1a = 0.f, ti = 0.f, dg = 0.f;
    if (act) {
      h1a = out[(size_t)n * 64 + c];  // agg + skip, staged by k_aggregate
      ti = t_int[n];
      dg = deg[n];
    }
    sh[wv][c] = h1a;
    __syncthreads();
    const float4* hr = (const float4*)&sh[wv][0];
    float xp = wxb;
    float acc = cbb;
#pragma unroll
    for (int j4 = 0; j4 < 16; ++j4) {
      float4 hv = hr[j4];
      xp  = fmaf(hv.x, wxreg[4 * j4 + 0], xp);
      xp  = fmaf(hv.y, wxreg[4 * j4 + 1], xp);
      xp  = fmaf(hv.z, wxreg[4 * j4 + 2], xp);
      xp  = fmaf(hv.w, wxreg[4 * j4 + 3], xp);
      acc = fmaf(hv.x, cbreg[4 * j4 + 0], acc);
      acc = fmaf(hv.y, cbreg[4 * j4 + 1], acc);
      acc = fmaf(hv.z, cbreg[4 * j4 + 2], acc);
      acc = fmaf(hv.w, cbreg[4 * j4 + 3], acc);
    }
    xp = tanhf(xp);
    const float ep0 = tanhf(fmaf(ti, A0, B0));
    const float ep1 = tanhf(fmaf(dg, A1, B1));
    float d0 = ep0 * xp, d1 = ep1 * xp;
#pragma unroll
    for (int msk = 32; msk >= 1; msk >>= 1) { d0 += __shfl_xor(d0, msk, 64); d1 += __shfl_xor(d1, msk, 64); }
    const float mx = fmaxf(d0, d1);
    const float e0 = expf(d0 - mx), e1 = expf(d1 - mx);
    const float sden = e0 + e1;
    const float s0 = e0 / sden, s1 = e1 / sden;
    acc = fmaf(s0, fmaf(ti, P0, Q0), acc);
    acc = fmaf(s1, fmaf(dg, P1, Q1), acc);
    float z0 = acc * ow0, z1 = acc * ow1;
#pragma unroll
    for (int msk = 32; msk >= 1; msk >>= 1) { z0 += __shfl_xor(z0, msk, 64); z1 += __shfl_xor(z1, msk, 64); }
    if (act) {
      out[(size_t)n * 64 + c] = acc;  // final h1
      if (c == 0) {
        z0 += ob0; z1 += ob1;
        const float mz = fmaxf(z0, z1);
        const float lse = mz + logf(expf(z0 - mz) + expf(z1 - mz));
        out[O1 + (size_t)n * 2 + 0] = z0 - lse;
        out[O1 + (size_t)n * 2 + 1] = z1 - lse;
        out[O2 + (size_t)n] = (float)y[n];
        out[O3 + (size_t)n] = mask_val(maskb, n);
      }
    }
    __syncthreads();
  }
}

extern "C" void kernel_launch(void* const* d_in, const int* in_sizes, int n_in,
                              void* d_out, int out_size, void* d_ws, size_t ws_size,
                              hipStream_t stream) {
  const float* x          = (const float*)d_in[0];
  const int*   ei         = (const int*)d_in[1];
  const float* node_time  = (const float*)d_in[2];
  const float* edge_time  = (const float*)d_in[3];
  const float* nmoti      = (const float*)d_in[4];
  const float* nod        = (const float*)d_in[5];
  const int*   y          = (const int*)d_in[6];
  const unsigned char* mask = (const unsigned char*)d_in[7];
  const float* time_w = (const float*)d_in[8];
  const float* time_b = (const float*)d_in[9];
  const float* tf_w   = (const float*)d_in[10];
  const float* tf_b   = (const float*)d_in[11];
  const float* deg_w  = (const float*)d_in[12];
  const float* deg_b  = (const float*)d_in[13];
  const float* lin_w  = (const float*)d_in[14];
  const float* lin_b  = (const float*)d_in[15];
  const float* Wq     = (const float*)d_in[16];
  const float* bq     = (const float*)d_in[17];
  const float* Wk     = (const float*)d_in[18];
  const float* bk     = (const float*)d_in[19];
  const float* Wv     = (const float*)d_in[20];
  const float* bv     = (const float*)d_in[21];
  const float* We     = (const float*)d_in[22];
  const float* be     = (const float*)d_in[23];
  const float* Wsk    = (const float*)d_in[24];
  const float* bsk    = (const float*)d_in[25];
  const float* wenc_w = (const float*)d_in[26];
  const float* wenc_b = (const float*)d_in[27];
  const float* wx_w   = (const float*)d_in[28];
  const float* wx_b   = (const float*)d_in[29];
  const float* comb_w = (const float*)d_in[30];
  const float* comb_b = (const float*)d_in[31];
  const float* out_w  = (const float*)d_in[32];
  const float* out_b  = (const float*)d_in[33];

  const int N = in_sizes[2];   // node_time
  const int E = in_sizes[3];   // edge_time
  const size_t N64 = (size_t)N * 64;

  float* q    = (float*)d_ws;
  float* k    = q + N64;
  float* v    = k + N64;
  float* rels = v + N64;
  int*   srcs = (int*)(rels + E);
  int*   counts = srcs + E;
  int*   rowptr = counts + N;        // N+1 ints
  int*   next   = rowptr + N + 1;
  int*   bsum   = next + N;          // ceil(N/256) ints (padded)
  float* cbuf   = (float*)(bsum + 4096);
  float* outf   = (float*)d_out;
  float* skip   = outf;  // stage skip in d_out[0:N*64)

  const int B = (N + 255) / 256;

  hipMemsetAsync(counts, 0, (size_t)N * sizeof(int), stream);

  k_precompute<<<1, 64, 0, stream>>>(tf_w, tf_b, deg_w, deg_b, wenc_w, wenc_b, comb_w, cbuf);

  const int ntiles = (N + 63) >> 6;
  k_node_proj<<<ntiles, 256, 0, stream>>>(x, lin_w, lin_b, Wq, bq, Wk, bk, Wv, bv, Wsk, bsk,
                                          be, q, k, v, skip, N);

  const int EB = (E + 255) / 256;
  k_hist<<<EB, 256, 0, stream>>>(ei, counts, E);
  k_scan1<<<B, 256, 0, stream>>>(counts, rowptr, bsum, N);
  k_scan2<<<1, 1024, 0, stream>>>(bsum, B);
  k_scan3<<<B, 256, 0, stream>>>(bsum, rowptr, next, N, E);
  k_fill<<<EB, 256, 0, stream>>>(ei, node_time, edge_time, next, srcs, rels, E);

  k_aggregate<<<(N + 3) / 4, 256, 0, stream>>>(rowptr, srcs, rels, q, k, v,
                                               time_w, time_b, We, outf, N);

  k_epilogue<<<2048, 256, 0, stream>>>(nmoti, nod, cbuf, wx_w, wx_b,
                                       comb_w, comb_b, out_w, out_b, y, mask, outf, N);
}

// Round 5
// 768.767 us; speedup vs baseline: 1.0742x; 1.0742x over previous
//
#include <hip/hip_runtime.h>
#include <hip/hip_fp16.h>

#define DEV __device__ __forceinline__

DEV float mask_val(const unsigned char* mb, int n) {
  // Detect train_mask storage from its first element: uint8 bool / int32 / float32.
  unsigned b0 = mb[0], b1 = mb[1], b2 = mb[2], b3 = mb[3];
  if (b0 <= 1u && b1 == b0 && b2 == b0 && b3 == b0) {
    return mb[n] ? 1.f : 0.f;                       // 1-byte bool
  } else if (b1 == 0u && b2 == 0u && b3 == 0u) {
    return ((const int*)mb)[n] ? 1.f : 0.f;         // int32
  } else {
    return (((const float*)mb)[n] != 0.f) ? 1.f : 0.f; // float32
  }
}

// ---------------- K0: rank-1 collapses of the context-attention algebra ----------------
__global__ void k_precompute(const float* __restrict__ tf_w, const float* __restrict__ tf_b,
                             const float* __restrict__ deg_w, const float* __restrict__ deg_b,
                             const float* __restrict__ wenc_w, const float* __restrict__ wenc_b,
                             const float* __restrict__ comb_w, float* __restrict__ cbuf) {
  int c = threadIdx.x;  // 64 threads
  float A0 = 0, B0 = 0, A1 = 0, B1 = 0, P0 = 0, Q0 = 0, P1 = 0, Q1 = 0;
  for (int j = 0; j < 64; ++j) {
    float w  = wenc_w[j * 64 + c];
    float cw = comb_w[(64 + j) * 64 + c];
    float twj = tf_w[j], tbj = tf_b[j], dwj = deg_w[j], dbj = deg_b[j];
    A0 += twj * w;  B0 += tbj * w;
    A1 += dwj * w;  B1 += dbj * w;
    P0 += twj * cw; Q0 += tbj * cw;
    P1 += dwj * cw; Q1 += dbj * cw;
  }
  float wb = wenc_b[c];
  cbuf[c]       = A0; cbuf[64 + c]  = B0 + wb;
  cbuf[128 + c] = A1; cbuf[192 + c] = B1 + wb;
  cbuf[256 + c] = P0; cbuf[320 + c] = Q0;
  cbuf[384 + c] = P1; cbuf[448 + c] = Q1;
}

// ---------------- K1: h = relu(x@lin); q_s, (k,v) packed fp16, skip ----------------
DEV float dot64_bcast(const float4* __restrict__ row, const float* __restrict__ w, float acc) {
#pragma unroll
  for (int j4 = 0; j4 < 16; ++j4) {
    float4 hv = row[j4];
    acc = fmaf(hv.x, w[4 * j4 + 0], acc);
    acc = fmaf(hv.y, w[4 * j4 + 1], acc);
    acc = fmaf(hv.z, w[4 * j4 + 2], acc);
    acc = fmaf(hv.w, w[4 * j4 + 3], acc);
  }
  return acc;
}

__global__ __launch_bounds__(256) void k_node_proj(
    const float* __restrict__ x,
    const float* __restrict__ lin_w, const float* __restrict__ lin_b,
    const float* __restrict__ Wq, const float* __restrict__ bq,
    const float* __restrict__ Wk, const float* __restrict__ bk,
    const float* __restrict__ Wv, const float* __restrict__ bv,
    const float* __restrict__ Wsk, const float* __restrict__ bsk,
    const float* __restrict__ be,
    float* __restrict__ q, __half* __restrict__ kvp,
    float* __restrict__ skipout, int N) {
  __shared__ float xs[4096];
  __shared__ float hs[4096];
  const int tid = threadIdx.x;
  const int c = tid & 63;
  const int rr0 = tid >> 6;
  const float bec = be[c];
  const float invs = 0.17677669529663687f;  // 1/sqrt(32)
  const int ntiles = (N + 63) >> 6;
  for (int tile = blockIdx.x; tile < ntiles; tile += gridDim.x) {
    const int base = tile << 6;
    for (int idx = tid; idx < 4096; idx += 256) {
      int n = base + (idx >> 6);
      xs[idx] = (n < N) ? x[(size_t)n * 64 + (idx & 63)] : 0.f;
    }
    __syncthreads();
    {
      float w[64];
#pragma unroll
      for (int j = 0; j < 64; ++j) w[j] = lin_w[j * 64 + c];
      const float bias = lin_b[c];
      for (int r = rr0; r < 64; r += 4) {
        float acc = dot64_bcast((const float4*)&xs[r << 6], w, bias);
        hs[(r << 6) + c] = fmaxf(acc, 0.f);
      }
    }
    __syncthreads();
    const float* Wm[4] = {Wq, Wk, Wv, Wsk};
    const float* bm[4] = {bq, bk, bv, bsk};
#pragma unroll 1
    for (int mm = 0; mm < 4; ++mm) {
      float w[64];
#pragma unroll
      for (int j = 0; j < 64; ++j) w[j] = Wm[mm][j * 64 + c];
      const float bias = bm[mm][c] + ((mm == 1 || mm == 2) ? bec : 0.f);
      for (int r = rr0; r < 64; r += 4) {
        const int n = base + r;
        float acc = dot64_bcast((const float4*)&hs[r << 6], w, bias);
        if (n < N) {
          if (mm == 0)      q[(size_t)n * 64 + c] = acc * invs;
          else if (mm == 3) skipout[(size_t)n * 64 + c] = acc;
          else              kvp[((size_t)n * 64 + c) * 2 + (mm - 1)] = __float2half_rn(acc);
        }
      }
    }
    __syncthreads();
  }
}

// ---------------- CSR build ----------------
__global__ __launch_bounds__(256) void k_hist(const int* __restrict__ ei, int* __restrict__ counts, int E) {
  int i = blockIdx.x * 256 + threadIdx.x;
  if (i < E) atomicAdd(&counts[ei[E + i]], 1);
}

__global__ __launch_bounds__(256) void k_scan1(const int* __restrict__ counts, int* __restrict__ excl,
                                               int* __restrict__ bsum, int N) {
  __shared__ int s[256];
  const int t = threadIdx.x;
  const int idx = blockIdx.x * 256 + t;
  int val = (idx < N) ? counts[idx] : 0;
  s[t] = val;
  __syncthreads();
  for (int d = 1; d < 256; d <<= 1) {
    int add = (t >= d) ? s[t - d] : 0;
    __syncthreads();
    s[t] += add;
    __syncthreads();
  }
  if (idx < N) excl[idx] = s[t] - val;
  if (t == 255) bsum[blockIdx.x] = s[255];
}

// parallel exclusive scan of the block sums (B <= 1024 fast path)
__global__ __launch_bounds__(1024) void k_scan2(int* __restrict__ bsum, int B) {
  __shared__ int sm[1024];
  const int t = threadIdx.x;
  if (B <= 1024) {
    int val = (t < B) ? bsum[t] : 0;
    sm[t] = val;
    __syncthreads();
    for (int d = 1; d < 1024; d <<= 1) {
      int add = (t >= d) ? sm[t - d] : 0;
      __syncthreads();
      sm[t] += add;
      __syncthreads();
    }
    if (t < B) bsum[t] = sm[t] - val;  // exclusive
  } else if (t == 0) {
    int acc = 0;
    for (int i = 0; i < B; ++i) { int tt = bsum[i]; bsum[i] = acc; acc += tt; }
  }
}

__global__ __launch_bounds__(256) void k_scan3(const int* __restrict__ bsum, int* __restrict__ rowptr,
                                               int* __restrict__ next, int N, int E) {
  int i = blockIdx.x * 256 + threadIdx.x;
  if (i < N) {
    int r = rowptr[i] + bsum[i >> 8];
    rowptr[i] = r;
    next[i] = r;
  }
  if (i == 0) rowptr[N] = E;
}

__global__ __launch_bounds__(256) void k_fill(const int* __restrict__ ei,
                                              const float* __restrict__ node_time,
                                              const float* __restrict__ edge_time,
                                              int* __restrict__ next, int2* __restrict__ er, int E) {
  int e = blockIdx.x * 256 + threadIdx.x;
  if (e < E) {
    int s = ei[e], d = ei[E + e];
    int pos = atomicAdd(&next[d], 1);
    er[pos] = make_int2(s, __float_as_int(node_time[s] - edge_time[e]));
  }
}

// ---------------- K2: CSR gather + online softmax aggregate ----------------
// one wave per dst node; lane = channel; (k,v) packed fp16 -> ONE 4B gather/lane/edge;
// (src,rel) packed int2 -> one uniform 8B load/edge; depth-3 pipeline; R3 occupancy.
__global__ __launch_bounds__(256) void k_aggregate(
    const int* __restrict__ rowptr, const int2* __restrict__ er,
    const float* __restrict__ q, const __half2* __restrict__ kvp,
    const float* __restrict__ time_w, const float* __restrict__ time_b,
    const float* __restrict__ We,
    float* __restrict__ h1, int N) {
  __shared__ float swS[4][64];
  const int tid = threadIdx.x;
  const int c = tid & 63;
  const int wv = tid >> 6;
  const float INV2PI = 0.15915494309189535f;
  float wcol[32], Gw[32];
#pragma unroll
  for (int j = 0; j < 32; ++j) wcol[j] = We[j * 64 + c];
#pragma unroll
  for (int j = 0; j < 32; ++j) Gw[j] = We[(c & 31) * 64 + (c & 32) + j];
  const float tw = time_w[c & 31] * INV2PI;
  const float tb = time_b[c & 31] * INV2PI;
  const int h32 = c & 32;
  const int n0 = blockIdx.x * 4 + wv;
  const int nstride = gridDim.x * 4;
  for (int n = n0; n < N; n += nstride) {
    const int start = rowptr[n];
    const int end = rowptr[n + 1];
    const float qc = q[(size_t)n * 64 + c];  // pre-scaled by 1/sqrt(32)
    // G[c] = sum_j q_s[n, h32+j] * We[c&31, h32+j]  (broadcast LDS reads)
    swS[wv][c] = qc;
    float Gc = 0.f;
#pragma unroll
    for (int j = 0; j < 32; ++j) Gc = fmaf(swS[wv][h32 | j], Gw[j], Gc);
    float m = -1e30f, den = 0.f, num = 0.f, S = 0.f;
    // depth-3 pipeline over packed kv gathers
    float r0 = 0.f, r1 = 0.f, r2 = 0.f;
    __half2 kv0 = __half2(), kv1 = __half2(), kv2 = __half2();
    if (start < end) {
      const int e1 = (start + 1 < end) ? start + 1 : end - 1;
      const int e2 = (start + 2 < end) ? start + 2 : end - 1;
      const int2 a = er[start], b = er[e1], d = er[e2];
      r0 = __int_as_float(a.y); r1 = __int_as_float(b.y); r2 = __int_as_float(d.y);
      kv0 = kvp[(size_t)a.x * 64 + c];
      kv1 = kvp[(size_t)b.x * 64 + c];
      kv2 = kvp[(size_t)d.x * 64 + c];
    }
    for (int e = start; e < end; ++e) {
      // compute edge e (slot0)
      const float kf = __half2float(kv0.x);
      const float vf = __half2float(kv0.y);
      float ang = fmaf(r0, tw, tb);
      ang = ang - floorf(ang);
      const float rv = __builtin_amdgcn_cosf(ang);   // cos(2*pi*ang)
      float p = fmaf(rv, Gc, qc * kf);
#pragma unroll
      for (int msk = 16; msk >= 1; msk >>= 1) p += __shfl_xor(p, msk, 64);
      const float mn = fmaxf(m, p);
      const float sc = __expf(m - mn);
      const float ea = __expf(p - mn);
      num = fmaf(num, sc, ea * vf);
      S   = fmaf(S, sc, ea * rv);
      den = fmaf(den, sc, ea);
      m = mn;
      // rotate + prefetch edge e+3 (wave-uniform branch)
      r0 = r1; kv0 = kv1;
      r1 = r2; kv1 = kv2;
      if (e + 3 < end) {
        const int2 nx = er[e + 3];
        r2 = __int_as_float(nx.y);
        kv2 = kvp[(size_t)nx.x * 64 + c];
      }
    }
    // e-projection contribution: econ[c] = sum_j We[j,c] * S[h32 + j]
    swS[wv][c] = S;
    float econ = 0.f;
#pragma unroll
    for (int j = 0; j < 32; ++j) econ = fmaf(swS[wv][h32 | j], wcol[j], econ);
    const float agg = (num + econ) / (den + 1e-16f);
    h1[(size_t)n * 64 + c] = agg + h1[(size_t)n * 64 + c];  // + staged skip
  }
}

// ---------------- K4: epilogue (context attention + combine + out + log_softmax) ----------------
__global__ __launch_bounds__(256) void k_epilogue(
    const float* __restrict__ t_int, const float* __restrict__ deg,
    const float* __restrict__ cbuf,
    const float* __restrict__ wx_w, const float* __restrict__ wx_b,
    const float* __restrict__ comb_w, const float* __restrict__ comb_b,
    const float* __restrict__ out_w, const float* __restrict__ out_b,
    const int* __restrict__ y, const unsigned char* __restrict__ maskb,
    float* __restrict__ out, int N) {
  __shared__ float sh[4][64];
  const int tid = threadIdx.x;
  const int c = tid & 63;
  const int wv = tid >> 6;
  float wxreg[64], cbreg[64];
#pragma unroll
  for (int j = 0; j < 64; ++j) { wxreg[j] = wx_w[j * 64 + c]; cbreg[j] = comb_w[j * 64 + c]; }
  const float A0 = cbuf[c], B0 = cbuf[64 + c], A1 = cbuf[128 + c], B1 = cbuf[192 + c];
  const float P0 = cbuf[256 + c], Q0 = cbuf[320 + c], P1 = cbuf[384 + c], Q1 = cbuf[448 + c];
  const float wxb = wx_b[c], cbb = comb_b[c];
  const float ow0 = out_w[c * 2 + 0], ow1 = out_w[c * 2 + 1];
  const float ob0 = out_b[0], ob1 = out_b[1];
  const size_t O1 = (size_t)N * 64;
  const size_t O2 = O1 + (size_t)N * 2;
  const size_t O3 = O2 + (size_t)N;
  const int ngroups = (N + 3) >> 2;
  for (int g = blockIdx.x; g < ngroups; g += gridDim.x) {
    const int n = g * 4 + wv;
    const bool act = n < N;
    float h1a = 0.f, ti = 0.f, dg = 0.f;
    if (act) {
      h1a = out[(size_t)n * 64 + c];  // agg + skip, staged by k_aggregate
      ti = t_int[n];
      dg = deg[n];
    }
    sh[wv][c] = h1a;
    __syncthreads();
    const float4* hr = (const float4*)&sh[wv][0];
    float xp = wxb;
    float acc = cbb;
#pragma unroll
    for (int j4 = 0; j4 < 16; ++j4) {
      float4 hv = hr[j4];
      xp  = fmaf(hv.x, wxreg[4 * j4 + 0], xp);
      xp  = fmaf(hv.y, wxreg[4 * j4 + 1], xp);
      xp  = fmaf(hv.z, wxreg[4 * j4 + 2], xp);
      xp  = fmaf(hv.w, wxreg[4 * j4 + 3], xp);
      acc = fmaf(hv.x, cbreg[4 * j4 + 0], acc);
      acc = fmaf(hv.y, cbreg[4 * j4 + 1], acc);
      acc = fmaf(hv.z, cbreg[4 * j4 + 2], acc);
      acc = fmaf(hv.w, cbreg[4 * j4 + 3], acc);
    }
    xp = tanhf(xp);
    const float ep0 = tanhf(fmaf(ti, A0, B0));
    const float ep1 = tanhf(fmaf(dg, A1, B1));
    float d0 = ep0 * xp, d1 = ep1 * xp;
#pragma unroll
    for (int msk = 32; msk >= 1; msk >>= 1) { d0 += __shfl_xor(d0, msk, 64); d1 += __shfl_xor(d1, msk, 64); }
    const float mx = fmaxf(d0, d1);
    const float e0 = expf(d0 - mx), e1 = expf(d1 - mx);
    const float sden = e0 + e1;
    const float s0 = e0 / sden, s1 = e1 / sden;
    acc = fmaf(s0, fmaf(ti, P0, Q0), acc);
    acc = fmaf(s1, fmaf(dg, P1, Q1), acc);
    float z0 = acc * ow0, z1 = acc * ow1;
#pragma unroll
    for (int msk = 32; msk >= 1; msk >>= 1) { z0 += __shfl_xor(z0, msk, 64); z1 += __shfl_xor(z1, msk, 64); }
    if (act) {
      out[(size_t)n * 64 + c] = acc;  // final h1
      if (c == 0) {
        z0 += ob0; z1 += ob1;
        const float mz = fmaxf(z0, z1);
        const float lse = mz + logf(expf(z0 - mz) + expf(z1 - mz));
        out[O1 + (size_t)n * 2 + 0] = z0 - lse;
        out[O1 + (size_t)n * 2 + 1] = z1 - lse;
        out[O2 + (size_t)n] = (float)y[n];
        out[O3 + (size_t)n] = mask_val(maskb, n);
      }
    }
    __syncthreads();
  }
}

extern "C" void kernel_launch(void* const* d_in, const int* in_sizes, int n_in,
                              void* d_out, int out_size, void* d_ws, size_t ws_size,
                              hipStream_t stream) {
  const float* x          = (const float*)d_in[0];
  const int*   ei         = (const int*)d_in[1];
  const float* node_time  = (const float*)d_in[2];
  const float* edge_time  = (const float*)d_in[3];
  const float* nmoti      = (const float*)d_in[4];
  const float* nod        = (const float*)d_in[5];
  const int*   y          = (const int*)d_in[6];
  const unsigned char* mask = (const unsigned char*)d_in[7];
  const float* time_w = (const float*)d_in[8];
  const float* time_b = (const float*)d_in[9];
  const float* tf_w   = (const float*)d_in[10];
  const float* tf_b   = (const float*)d_in[11];
  const float* deg_w  = (const float*)d_in[12];
  const float* deg_b  = (const float*)d_in[13];
  const float* lin_w  = (const float*)d_in[14];
  const float* lin_b  = (const float*)d_in[15];
  const float* Wq     = (const float*)d_in[16];
  const float* bq     = (const float*)d_in[17];
  const float* Wk     = (const float*)d_in[18];
  const float* bk     = (const float*)d_in[19];
  const float* Wv     = (const float*)d_in[20];
  const float* bv     = (const float*)d_in[21];
  const float* We     = (const float*)d_in[22];
  const float* be     = (const float*)d_in[23];
  const float* Wsk    = (const float*)d_in[24];
  const float* bsk    = (const float*)d_in[25];
  const float* wenc_w = (const float*)d_in[26];
  const float* wenc_b = (const float*)d_in[27];
  const float* wx_w   = (const float*)d_in[28];
  const float* wx_b   = (const float*)d_in[29];
  const float* comb_w = (const float*)d_in[30];
  const float* comb_b = (const float*)d_in[31];
  const float* out_w  = (const float*)d_in[32];
  const float* out_b  = (const float*)d_in[33];

  const int N = in_sizes[2];   // node_time
  const int E = in_sizes[3];   // edge_time
  const size_t N64 = (size_t)N * 64;

  float*   q    = (float*)d_ws;
  __half*  kvp  = (__half*)(q + N64);        // N64 half2 = N64 * 4B
  int2*    er   = (int2*)((char*)kvp + N64 * sizeof(__half2));
  int*     counts = (int*)(er + E);
  int*     rowptr = counts + N;              // N+1 ints
  int*     next   = rowptr + N + 1;
  int*     bsum   = next + N;                // ceil(N/256) ints (padded)
  float*   cbuf   = (float*)(bsum + 4096);
  float*   outf   = (float*)d_out;
  float*   skip   = outf;  // stage skip in d_out[0:N*64)

  const int B = (N + 255) / 256;

  hipMemsetAsync(counts, 0, (size_t)N * sizeof(int), stream);

  k_precompute<<<1, 64, 0, stream>>>(tf_w, tf_b, deg_w, deg_b, wenc_w, wenc_b, comb_w, cbuf);

  const int ntiles = (N + 63) >> 6;
  k_node_proj<<<ntiles, 256, 0, stream>>>(x, lin_w, lin_b, Wq, bq, Wk, bk, Wv, bv, Wsk, bsk,
                                          be, q, kvp, skip, N);

  const int EB = (E + 255) / 256;
  k_hist<<<EB, 256, 0, stream>>>(ei, counts, E);
  k_scan1<<<B, 256, 0, stream>>>(counts, rowptr, bsum, N);
  k_scan2<<<1, 1024, 0, stream>>>(bsum, B);
  k_scan3<<<B, 256, 0, stream>>>(bsum, rowptr, next, N, E);
  k_fill<<<EB, 256, 0, stream>>>(ei, node_time, edge_time, next, er, E);

  k_aggregate<<<(N + 3) / 4, 256, 0, stream>>>(rowptr, er, q, (const __half2*)kvp,
                                               time_w, time_b, We, outf, N);

  k_epilogue<<<2048, 256, 0, stream>>>(nmoti, nod, cbuf, wx_w, wx_b,
                                       comb_w, comb_b, out_w, out_b, y, mask, outf, N);
}

// Round 6
// 753.002 us; speedup vs baseline: 1.0967x; 1.0209x over previous
//
#include <hip/hip_runtime.h>
#include <hip/hip_fp16.h>

#define DEV __device__ __forceinline__

DEV float mask_val(const unsigned char* mb, int n) {
  // Detect train_mask storage from its first element: uint8 bool / int32 / float32.
  unsigned b0 = mb[0], b1 = mb[1], b2 = mb[2], b3 = mb[3];
  if (b0 <= 1u && b1 == b0 && b2 == b0 && b3 == b0) {
    return mb[n] ? 1.f : 0.f;                       // 1-byte bool
  } else if (b1 == 0u && b2 == 0u && b3 == 0u) {
    return ((const int*)mb)[n] ? 1.f : 0.f;         // int32
  } else {
    return (((const float*)mb)[n] != 0.f) ? 1.f : 0.f; // float32
  }
}

// ---------------- K0: rank-1 collapses of the context-attention algebra ----------------
__global__ void k_precompute(const float* __restrict__ tf_w, const float* __restrict__ tf_b,
                             const float* __restrict__ deg_w, const float* __restrict__ deg_b,
                             const float* __restrict__ wenc_w, const float* __restrict__ wenc_b,
                             const float* __restrict__ comb_w, float* __restrict__ cbuf) {
  int c = threadIdx.x;  // 64 threads
  float A0 = 0, B0 = 0, A1 = 0, B1 = 0, P0 = 0, Q0 = 0, P1 = 0, Q1 = 0;
  for (int j = 0; j < 64; ++j) {
    float w  = wenc_w[j * 64 + c];
    float cw = comb_w[(64 + j) * 64 + c];
    float twj = tf_w[j], tbj = tf_b[j], dwj = deg_w[j], dbj = deg_b[j];
    A0 += twj * w;  B0 += tbj * w;
    A1 += dwj * w;  B1 += dbj * w;
    P0 += twj * cw; Q0 += tbj * cw;
    P1 += dwj * cw; Q1 += dbj * cw;
  }
  float wb = wenc_b[c];
  cbuf[c]       = A0; cbuf[64 + c]  = B0 + wb;
  cbuf[128 + c] = A1; cbuf[192 + c] = B1 + wb;
  cbuf[256 + c] = P0; cbuf[320 + c] = Q0;
  cbuf[384 + c] = P1; cbuf[448 + c] = Q1;
}

// ---------------- K1: h = relu(x@lin); q_s, (k,v) packed fp16 (coalesced half2), skip ----------------
DEV float dot64_bcast(const float4* __restrict__ row, const float* __restrict__ w, float acc) {
#pragma unroll
  for (int j4 = 0; j4 < 16; ++j4) {
    float4 hv = row[j4];
    acc = fmaf(hv.x, w[4 * j4 + 0], acc);
    acc = fmaf(hv.y, w[4 * j4 + 1], acc);
    acc = fmaf(hv.z, w[4 * j4 + 2], acc);
    acc = fmaf(hv.w, w[4 * j4 + 3], acc);
  }
  return acc;
}

__global__ __launch_bounds__(256) void k_node_proj(
    const float* __restrict__ x,
    const float* __restrict__ lin_w, const float* __restrict__ lin_b,
    const float* __restrict__ Wq, const float* __restrict__ bq,
    const float* __restrict__ Wk, const float* __restrict__ bk,
    const float* __restrict__ Wv, const float* __restrict__ bv,
    const float* __restrict__ Wsk, const float* __restrict__ bsk,
    const float* __restrict__ be,
    float* __restrict__ q, __half2* __restrict__ kvp,
    float* __restrict__ skipout, int N) {
  __shared__ float xs[4096];   // x tile; reused to stage the k column between mm=1 and mm=2
  __shared__ float hs[4096];
  const int tid = threadIdx.x;
  const int c = tid & 63;
  const int rr0 = tid >> 6;
  const float bec = be[c];
  const float invs = 0.17677669529663687f;  // 1/sqrt(32)
  const int ntiles = (N + 63) >> 6;
  for (int tile = blockIdx.x; tile < ntiles; tile += gridDim.x) {
    const int base = tile << 6;
    for (int idx = tid; idx < 4096; idx += 256) {
      int n = base + (idx >> 6);
      xs[idx] = (n < N) ? x[(size_t)n * 64 + (idx & 63)] : 0.f;
    }
    __syncthreads();
    {
      float w[64];
#pragma unroll
      for (int j = 0; j < 64; ++j) w[j] = lin_w[j * 64 + c];
      const float bias = lin_b[c];
      for (int r = rr0; r < 64; r += 4) {
        float acc = dot64_bcast((const float4*)&xs[r << 6], w, bias);
        hs[(r << 6) + c] = fmaxf(acc, 0.f);
      }
    }
    __syncthreads();
    const float* Wm[4] = {Wq, Wk, Wv, Wsk};
    const float* bm[4] = {bq, bk, bv, bsk};
#pragma unroll 1
    for (int mm = 0; mm < 4; ++mm) {
      float w[64];
#pragma unroll
      for (int j = 0; j < 64; ++j) w[j] = Wm[mm][j * 64 + c];
      const float bias = bm[mm][c] + ((mm == 1 || mm == 2) ? bec : 0.f);
      for (int r = rr0; r < 64; r += 4) {
        const int n = base + r;
        float acc = dot64_bcast((const float4*)&hs[r << 6], w, bias);
        if (mm == 0) {
          if (n < N) q[(size_t)n * 64 + c] = acc * invs;
        } else if (mm == 1) {
          xs[(r << 6) + c] = acc;           // stage k (same thread reads it at mm==2)
        } else if (mm == 2) {
          if (n < N)
            kvp[(size_t)n * 64 + c] =
                __halves2half2(__float2half_rn(xs[(r << 6) + c]), __float2half_rn(acc));
        } else {
          if (n < N) skipout[(size_t)n * 64 + c] = acc;
        }
      }
    }
    __syncthreads();
  }
}

// ---------------- CSR build ----------------
__global__ __launch_bounds__(256) void k_hist(const int* __restrict__ ei, int* __restrict__ counts, int E) {
  int i = blockIdx.x * 256 + threadIdx.x;
  if (i < E) atomicAdd(&counts[ei[E + i]], 1);
}

__global__ __launch_bounds__(256) void k_scan1(const int* __restrict__ counts, int* __restrict__ excl,
                                               int* __restrict__ bsum, int N) {
  __shared__ int s[256];
  const int t = threadIdx.x;
  const int idx = blockIdx.x * 256 + t;
  int val = (idx < N) ? counts[idx] : 0;
  s[t] = val;
  __syncthreads();
  for (int d = 1; d < 256; d <<= 1) {
    int add = (t >= d) ? s[t - d] : 0;
    __syncthreads();
    s[t] += add;
    __syncthreads();
  }
  if (idx < N) excl[idx] = s[t] - val;
  if (t == 255) bsum[blockIdx.x] = s[255];
}

// parallel exclusive scan of the block sums (B <= 1024 fast path)
__global__ __launch_bounds__(1024) void k_scan2(int* __restrict__ bsum, int B) {
  __shared__ int sm[1024];
  const int t = threadIdx.x;
  if (B <= 1024) {
    int val = (t < B) ? bsum[t] : 0;
    sm[t] = val;
    __syncthreads();
    for (int d = 1; d < 1024; d <<= 1) {
      int add = (t >= d) ? sm[t - d] : 0;
      __syncthreads();
      sm[t] += add;
      __syncthreads();
    }
    if (t < B) bsum[t] = sm[t] - val;  // exclusive
  } else if (t == 0) {
    int acc = 0;
    for (int i = 0; i < B; ++i) { int tt = bsum[i]; bsum[i] = acc; acc += tt; }
  }
}

__global__ __launch_bounds__(256) void k_scan3(const int* __restrict__ bsum, int* __restrict__ rowptr,
                                               int* __restrict__ next, int N, int E) {
  int i = blockIdx.x * 256 + threadIdx.x;
  if (i < N) {
    int r = rowptr[i] + bsum[i >> 8];
    rowptr[i] = r;
    next[i] = r;
  }
  if (i == 0) rowptr[N] = E;
}

__global__ __launch_bounds__(256) void k_fill(const int* __restrict__ ei,
                                              const float* __restrict__ node_time,
                                              const float* __restrict__ edge_time,
                                              int* __restrict__ next, int2* __restrict__ er, int E) {
  int e = blockIdx.x * 256 + threadIdx.x;
  if (e < E) {
    int s = ei[e], d = ei[E + e];
    int pos = atomicAdd(&next[d], 1);
    er[pos] = make_int2(s, __float_as_int(node_time[s] - edge_time[e]));
  }
}

// ---------------- K2: CSR gather + online softmax aggregate ----------------
// PERSISTENT grid (768 blocks = ~3072 waves, matching measured residency): each wave
// loops ~33 strided nodes so per-wave work concentrates (CLT) and round-stragglers vanish.
__global__ __launch_bounds__(256) void k_aggregate(
    const int* __restrict__ rowptr, const int2* __restrict__ er,
    const float* __restrict__ q, const __half2* __restrict__ kvp,
    const float* __restrict__ time_w, const float* __restrict__ time_b,
    const float* __restrict__ We,
    float* __restrict__ h1, int N) {
  __shared__ float swS[4][64];
  const int tid = threadIdx.x;
  const int c = tid & 63;
  const int wv = tid >> 6;
  const float INV2PI = 0.15915494309189535f;
  float wcol[32], Gw[32];
#pragma unroll
  for (int j = 0; j < 32; ++j) wcol[j] = We[j * 64 + c];
#pragma unroll
  for (int j = 0; j < 32; ++j) Gw[j] = We[(c & 31) * 64 + (c & 32) + j];
  const float tw = time_w[c & 31] * INV2PI;
  const float tb = time_b[c & 31] * INV2PI;
  const int h32 = c & 32;
  const int n0 = blockIdx.x * 4 + wv;
  const int nstride = gridDim.x * 4;
  for (int n = n0; n < N; n += nstride) {
    const int start = rowptr[n];
    const int end = rowptr[n + 1];
    const float qc = q[(size_t)n * 64 + c];  // pre-scaled by 1/sqrt(32)
    // G[c] = sum_j q_s[n, h32+j] * We[c&31, h32+j]  (broadcast LDS reads)
    swS[wv][c] = qc;
    float Gc = 0.f;
#pragma unroll
    for (int j = 0; j < 32; ++j) Gc = fmaf(swS[wv][h32 | j], Gw[j], Gc);
    float m = -1e30f, den = 0.f, num = 0.f, S = 0.f;
    // depth-3 pipeline over packed kv gathers
    float r0 = 0.f, r1 = 0.f, r2 = 0.f;
    __half2 kv0 = __half2(), kv1 = __half2(), kv2 = __half2();
    if (start < end) {
      const int e1 = (start + 1 < end) ? start + 1 : end - 1;
      const int e2 = (start + 2 < end) ? start + 2 : end - 1;
      const int2 a = er[start], b = er[e1], d = er[e2];
      r0 = __int_as_float(a.y); r1 = __int_as_float(b.y); r2 = __int_as_float(d.y);
      kv0 = kvp[(size_t)a.x * 64 + c];
      kv1 = kvp[(size_t)b.x * 64 + c];
      kv2 = kvp[(size_t)d.x * 64 + c];
    }
    for (int e = start; e < end; ++e) {
      // compute edge e (slot0)
      const float kf = __half2float(kv0.x);
      const float vf = __half2float(kv0.y);
      float ang = fmaf(r0, tw, tb);
      ang = ang - floorf(ang);
      const float rv = __builtin_amdgcn_cosf(ang);   // cos(2*pi*ang)
      float p = fmaf(rv, Gc, qc * kf);
#pragma unroll
      for (int msk = 16; msk >= 1; msk >>= 1) p += __shfl_xor(p, msk, 64);
      const float mn = fmaxf(m, p);
      const float sc = __expf(m - mn);
      const float ea = __expf(p - mn);
      num = fmaf(num, sc, ea * vf);
      S   = fmaf(S, sc, ea * rv);
      den = fmaf(den, sc, ea);
      m = mn;
      // rotate + prefetch edge e+3 (wave-uniform branch)
      r0 = r1; kv0 = kv1;
      r1 = r2; kv1 = kv2;
      if (e + 3 < end) {
        const int2 nx = er[e + 3];
        r2 = __int_as_float(nx.y);
        kv2 = kvp[(size_t)nx.x * 64 + c];
      }
    }
    // e-projection contribution: econ[c] = sum_j We[j,c] * S[h32 + j]
    swS[wv][c] = S;
    float econ = 0.f;
#pragma unroll
    for (int j = 0; j < 32; ++j) econ = fmaf(swS[wv][h32 | j], wcol[j], econ);
    const float agg = (num + econ) / (den + 1e-16f);
    h1[(size_t)n * 64 + c] = agg + h1[(size_t)n * 64 + c];  // + staged skip
  }
}

// ---------------- K4: epilogue (context attention + combine + out + log_softmax) ----------------
__global__ __launch_bounds__(256) void k_epilogue(
    const float* __restrict__ t_int, const float* __restrict__ deg,
    const float* __restrict__ cbuf,
    const float* __restrict__ wx_w, const float* __restrict__ wx_b,
    const float* __restrict__ comb_w, const float* __restrict__ comb_b,
    const float* __restrict__ out_w, const float* __restrict__ out_b,
    const int* __restrict__ y, const unsigned char* __restrict__ maskb,
    float* __restrict__ out, int N) {
  __shared__ float sh[4][64];
  const int tid = threadIdx.x;
  const int c = tid & 63;
  const int wv = tid >> 6;
  float wxreg[64], cbreg[64];
#pragma unroll
  for (int j = 0; j < 64; ++j) { wxreg[j] = wx_w[j * 64 + c]; cbreg[j] = comb_w[j * 64 + c]; }
  const float A0 = cbuf[c], B0 = cbuf[64 + c], A1 = cbuf[128 + c], B1 = cbuf[192 + c];
  const float P0 = cbuf[256 + c], Q0 = cbuf[320 + c], P1 = cbuf[384 + c], Q1 = cbuf[448 + c];
  const float wxb = wx_b[c], cbb = comb_b[c];
  const float ow0 = out_w[c * 2 + 0], ow1 = out_w[c * 2 + 1];
  const float ob0 = out_b[0], ob1 = out_b[1];
  const size_t O1 = (size_t)N * 64;
  const size_t O2 = O1 + (size_t)N * 2;
  const size_t O3 = O2 + (size_t)N;
  const int ngroups = (N + 3) >> 2;
  for (int g = blockIdx.x; g < ngroups; g += gridDim.x) {
    const int n = g * 4 + wv;
    const bool act = n < N;
    float h1a = 0.f, ti = 0.f, dg = 0.f;
    if (act) {
      h1a = out[(size_t)n * 64 + c];  // agg + skip, staged by k_aggregate
      ti = t_int[n];
      dg = deg[n];
    }
    sh[wv][c] = h1a;
    __syncthreads();
    const float4* hr = (const float4*)&sh[wv][0];
    float xp = wxb;
    float acc = cbb;
#pragma unroll
    for (int j4 = 0; j4 < 16; ++j4) {
      float4 hv = hr[j4];
      xp  = fmaf(hv.x, wxreg[4 * j4 + 0], xp);
      xp  = fmaf(hv.y, wxreg[4 * j4 + 1], xp);
      xp  = fmaf(hv.z, wxreg[4 * j4 + 2], xp);
      xp  = fmaf(hv.w, wxreg[4 * j4 + 3], xp);
      acc = fmaf(hv.x, cbreg[4 * j4 + 0], acc);
      acc = fmaf(hv.y, cbreg[4 * j4 + 1], acc);
      acc = fmaf(hv.z, cbreg[4 * j4 + 2], acc);
      acc = fmaf(hv.w, cbreg[4 * j4 + 3], acc);
    }
    xp = tanhf(xp);
    const float ep0 = tanhf(fmaf(ti, A0, B0));
    const float ep1 = tanhf(fmaf(dg, A1, B1));
    float d0 = ep0 * xp, d1 = ep1 * xp;
#pragma unroll
    for (int msk = 32; msk >= 1; msk >>= 1) { d0 += __shfl_xor(d0, msk, 64); d1 += __shfl_xor(d1, msk, 64); }
    const float mx = fmaxf(d0, d1);
    const float e0 = expf(d0 - mx), e1 = expf(d1 - mx);
    const float sden = e0 + e1;
    const float s0 = e0 / sden, s1 = e1 / sden;
    acc = fmaf(s0, fmaf(ti, P0, Q0), acc);
    acc = fmaf(s1, fmaf(dg, P1, Q1), acc);
    float z0 = acc * ow0, z1 = acc * ow1;
#pragma unroll
    for (int msk = 32; msk >= 1; msk >>= 1) { z0 += __shfl_xor(z0, msk, 64); z1 += __shfl_xor(z1, msk, 64); }
    if (act) {
      out[(size_t)n * 64 + c] = acc;  // final h1
      if (c == 0) {
        z0 += ob0; z1 += ob1;
        const float mz = fmaxf(z0, z1);
        const float lse = mz + logf(expf(z0 - mz) + expf(z1 - mz));
        out[O1 + (size_t)n * 2 + 0] = z0 - lse;
        out[O1 + (size_t)n * 2 + 1] = z1 - lse;
        out[O2 + (size_t)n] = (float)y[n];
        out[O3 + (size_t)n] = mask_val(maskb, n);
      }
    }
    __syncthreads();
  }
}

extern "C" void kernel_launch(void* const* d_in, const int* in_sizes, int n_in,
                              void* d_out, int out_size, void* d_ws, size_t ws_size,
                              hipStream_t stream) {
  const float* x          = (const float*)d_in[0];
  const int*   ei         = (const int*)d_in[1];
  const float* node_time  = (const float*)d_in[2];
  const float* edge_time  = (const float*)d_in[3];
  const float* nmoti      = (const float*)d_in[4];
  const float* nod        = (const float*)d_in[5];
  const int*   y          = (const int*)d_in[6];
  const unsigned char* mask = (const unsigned char*)d_in[7];
  const float* time_w = (const float*)d_in[8];
  const float* time_b = (const float*)d_in[9];
  const float* tf_w   = (const float*)d_in[10];
  const float* tf_b   = (const float*)d_in[11];
  const float* deg_w  = (const float*)d_in[12];
  const float* deg_b  = (const float*)d_in[13];
  const float* lin_w  = (const float*)d_in[14];
  const float* lin_b  = (const float*)d_in[15];
  const float* Wq     = (const float*)d_in[16];
  const float* bq     = (const float*)d_in[17];
  const float* Wk     = (const float*)d_in[18];
  const float* bk     = (const float*)d_in[19];
  const float* Wv     = (const float*)d_in[20];
  const float* bv     = (const float*)d_in[21];
  const float* We     = (const float*)d_in[22];
  const float* be     = (const float*)d_in[23];
  const float* Wsk    = (const float*)d_in[24];
  const float* bsk    = (const float*)d_in[25];
  const float* wenc_w = (const float*)d_in[26];
  const float* wenc_b = (const float*)d_in[27];
  const float* wx_w   = (const float*)d_in[28];
  const float* wx_b   = (const float*)d_in[29];
  const float* comb_w = (const float*)d_in[30];
  const float* comb_b = (const float*)d_in[31];
  const float* out_w  = (const float*)d_in[32];
  const float* out_b  = (const float*)d_in[33];

  const int N = in_sizes[2];   // node_time
  const int E = in_sizes[3];   // edge_time
  const size_t N64 = (size_t)N * 64;

  float*   q    = (float*)d_ws;
  __half2* kvp  = (__half2*)(q + N64);       // N64 half2 = N64 * 4B
  int2*    er   = (int2*)((char*)kvp + N64 * sizeof(__half2));
  int*     counts = (int*)(er + E);
  int*     rowptr = counts + N;              // N+1 ints
  int*     next   = rowptr + N + 1;
  int*     bsum   = next + N;                // ceil(N/256) ints (padded)
  float*   cbuf   = (float*)(bsum + 4096);
  float*   outf   = (float*)d_out;
  float*   skip   = outf;  // stage skip in d_out[0:N*64)

  const int B = (N + 255) / 256;

  hipMemsetAsync(counts, 0, (size_t)N * sizeof(int), stream);

  k_precompute<<<1, 64, 0, stream>>>(tf_w, tf_b, deg_w, deg_b, wenc_w, wenc_b, comb_w, cbuf);

  const int ntiles = (N + 63) >> 6;
  k_node_proj<<<ntiles, 256, 0, stream>>>(x, lin_w, lin_b, Wq, bq, Wk, bk, Wv, bv, Wsk, bsk,
                                          be, q, kvp, skip, N);

  const int EB = (E + 255) / 256;
  k_hist<<<EB, 256, 0, stream>>>(ei, counts, E);
  k_scan1<<<B, 256, 0, stream>>>(counts, rowptr, bsum, N);
  k_scan2<<<1, 1024, 0, stream>>>(bsum, B);
  k_scan3<<<B, 256, 0, stream>>>(bsum, rowptr, next, N, E);
  k_fill<<<EB, 256, 0, stream>>>(ei, node_time, edge_time, next, er, E);

  // persistent grid: ~3072 waves (matches measured residency), ~33 nodes/wave
  int agb = 768;
  if (agb > (N + 3) / 4) agb = (N + 3) / 4;
  k_aggregate<<<agb, 256, 0, stream>>>(rowptr, er, q, kvp, time_w, time_b, We, outf, N);

  k_epilogue<<<2048, 256, 0, stream>>>(nmoti, nod, cbuf, wx_w, wx_b,
                                       comb_w, comb_b, out_w, out_b, y, mask, outf, N);
}

// Round 7
// 697.879 us; speedup vs baseline: 1.1834x; 1.0790x over previous
//
#include <hip/hip_runtime.h>
#include <hip/hip_fp16.h>

#define DEV __device__ __forceinline__

DEV float mask_val(const unsigned char* mb, int n) {
  // Detect train_mask storage from its first element: uint8 bool / int32 / float32.
  unsigned b0 = mb[0], b1 = mb[1], b2 = mb[2], b3 = mb[3];
  if (b0 <= 1u && b1 == b0 && b2 == b0 && b3 == b0) {
    return mb[n] ? 1.f : 0.f;                       // 1-byte bool
  } else if (b1 == 0u && b2 == 0u && b3 == 0u) {
    return ((const int*)mb)[n] ? 1.f : 0.f;         // int32
  } else {
    return (((const float*)mb)[n] != 0.f) ? 1.f : 0.f; // float32
  }
}

// ---------------- K0: rank-1 collapses of the context-attention algebra ----------------
__global__ void k_precompute(const float* __restrict__ tf_w, const float* __restrict__ tf_b,
                             const float* __restrict__ deg_w, const float* __restrict__ deg_b,
                             const float* __restrict__ wenc_w, const float* __restrict__ wenc_b,
                             const float* __restrict__ comb_w, float* __restrict__ cbuf) {
  int c = threadIdx.x;  // 64 threads
  float A0 = 0, B0 = 0, A1 = 0, B1 = 0, P0 = 0, Q0 = 0, P1 = 0, Q1 = 0;
  for (int j = 0; j < 64; ++j) {
    float w  = wenc_w[j * 64 + c];
    float cw = comb_w[(64 + j) * 64 + c];
    float twj = tf_w[j], tbj = tf_b[j], dwj = deg_w[j], dbj = deg_b[j];
    A0 += twj * w;  B0 += tbj * w;
    A1 += dwj * w;  B1 += dbj * w;
    P0 += twj * cw; Q0 += tbj * cw;
    P1 += dwj * cw; Q1 += dbj * cw;
  }
  float wb = wenc_b[c];
  cbuf[c]       = A0; cbuf[64 + c]  = B0 + wb;
  cbuf[128 + c] = A1; cbuf[192 + c] = B1 + wb;
  cbuf[256 + c] = P0; cbuf[320 + c] = Q0;
  cbuf[384 + c] = P1; cbuf[448 + c] = Q1;
}

// ---------------- K1: h = relu(x@lin); q_s, (k,v) packed fp16 (coalesced half2), skip ----------------
// Two rows x two accumulators = 4 independent FMA chains of length 16 (was: one chain of 64).
DEV void dot64_x2(const float* __restrict__ rowA, const float* __restrict__ rowB,
                  const float* __restrict__ w, float bias, float& outA, float& outB) {
  const float4* a4 = (const float4*)rowA;
  const float4* b4 = (const float4*)rowB;
  float a0 = bias, a1 = 0.f, b0 = bias, b1 = 0.f;
#pragma unroll
  for (int j = 0; j < 16; j += 2) {
    float4 va0 = a4[j], va1 = a4[j + 1];
    float4 vb0 = b4[j], vb1 = b4[j + 1];
    a0 = fmaf(va0.x, w[4 * j + 0], a0);
    a0 = fmaf(va0.y, w[4 * j + 1], a0);
    a0 = fmaf(va0.z, w[4 * j + 2], a0);
    a0 = fmaf(va0.w, w[4 * j + 3], a0);
    a1 = fmaf(va1.x, w[4 * j + 4], a1);
    a1 = fmaf(va1.y, w[4 * j + 5], a1);
    a1 = fmaf(va1.z, w[4 * j + 6], a1);
    a1 = fmaf(va1.w, w[4 * j + 7], a1);
    b0 = fmaf(vb0.x, w[4 * j + 0], b0);
    b0 = fmaf(vb0.y, w[4 * j + 1], b0);
    b0 = fmaf(vb0.z, w[4 * j + 2], b0);
    b0 = fmaf(vb0.w, w[4 * j + 3], b0);
    b1 = fmaf(vb1.x, w[4 * j + 4], b1);
    b1 = fmaf(vb1.y, w[4 * j + 5], b1);
    b1 = fmaf(vb1.z, w[4 * j + 6], b1);
    b1 = fmaf(vb1.w, w[4 * j + 7], b1);
  }
  outA = a0 + a1;
  outB = b0 + b1;
}

__global__ __launch_bounds__(256) void k_node_proj(
    const float* __restrict__ x,
    const float* __restrict__ lin_w, const float* __restrict__ lin_b,
    const float* __restrict__ Wq, const float* __restrict__ bq,
    const float* __restrict__ Wk, const float* __restrict__ bk,
    const float* __restrict__ Wv, const float* __restrict__ bv,
    const float* __restrict__ Wsk, const float* __restrict__ bsk,
    const float* __restrict__ be,
    float* __restrict__ q, __half2* __restrict__ kvp,
    float* __restrict__ skipout, int N) {
  __shared__ float xs[4096];   // x tile; reused to stage the k column between mm=1 and mm=2
  __shared__ float hs[4096];
  const int tid = threadIdx.x;
  const int c = tid & 63;
  const int rr0 = tid >> 6;
  const float bec = be[c];
  const float invs = 0.17677669529663687f;  // 1/sqrt(32)
  const int ntiles = (N + 63) >> 6;
  for (int tile = blockIdx.x; tile < ntiles; tile += gridDim.x) {
    const int base = tile << 6;
    if (base + 64 <= N) {
      const float4* x4 = (const float4*)x;
      float4* xs4 = (float4*)xs;
      for (int idx = tid; idx < 1024; idx += 256) xs4[idx] = x4[(size_t)base * 16 + idx];
    } else {
      for (int idx = tid; idx < 4096; idx += 256) {
        int n = base + (idx >> 6);
        xs[idx] = (n < N) ? x[(size_t)n * 64 + (idx & 63)] : 0.f;
      }
    }
    __syncthreads();
    {
      float w[64];
#pragma unroll
      for (int j = 0; j < 64; ++j) w[j] = lin_w[j * 64 + c];
      const float bias = lin_b[c];
#pragma unroll 1
      for (int rr = 0; rr < 8; ++rr) {
        const int rA = rr0 + rr * 4, rB = rA + 32;
        float hA, hB;
        dot64_x2(&xs[rA << 6], &xs[rB << 6], w, bias, hA, hB);
        hs[(rA << 6) + c] = fmaxf(hA, 0.f);
        hs[(rB << 6) + c] = fmaxf(hB, 0.f);
      }
    }
    __syncthreads();
    const float* Wm[4] = {Wq, Wk, Wv, Wsk};
    const float* bm[4] = {bq, bk, bv, bsk};
#pragma unroll 1
    for (int mm = 0; mm < 4; ++mm) {
      float w[64];
#pragma unroll
      for (int j = 0; j < 64; ++j) w[j] = Wm[mm][j * 64 + c];
      const float bias = bm[mm][c] + ((mm == 1 || mm == 2) ? bec : 0.f);
#pragma unroll 1
      for (int rr = 0; rr < 8; ++rr) {
        const int rA = rr0 + rr * 4, rB = rA + 32;
        const int nA = base + rA, nB = base + rB;
        float accA, accB;
        dot64_x2(&hs[rA << 6], &hs[rB << 6], w, bias, accA, accB);
        if (mm == 0) {
          if (nA < N) q[(size_t)nA * 64 + c] = accA * invs;
          if (nB < N) q[(size_t)nB * 64 + c] = accB * invs;
        } else if (mm == 1) {
          xs[(rA << 6) + c] = accA;         // stage k (same thread reads it at mm==2)
          xs[(rB << 6) + c] = accB;
        } else if (mm == 2) {
          if (nA < N)
            kvp[(size_t)nA * 64 + c] =
                __halves2half2(__float2half_rn(xs[(rA << 6) + c]), __float2half_rn(accA));
          if (nB < N)
            kvp[(size_t)nB * 64 + c] =
                __halves2half2(__float2half_rn(xs[(rB << 6) + c]), __float2half_rn(accB));
        } else {
          if (nA < N) skipout[(size_t)nA * 64 + c] = accA;
          if (nB < N) skipout[(size_t)nB * 64 + c] = accB;
        }
      }
    }
    __syncthreads();
  }
}

// ---------------- CSR build ----------------
__global__ __launch_bounds__(256) void k_hist(const int* __restrict__ ei, int* __restrict__ counts, int E) {
  int i = blockIdx.x * 256 + threadIdx.x;
  if (i < E) atomicAdd(&counts[ei[E + i]], 1);
}

__global__ __launch_bounds__(256) void k_scan1(const int* __restrict__ counts, int* __restrict__ excl,
                                               int* __restrict__ bsum, int N) {
  __shared__ int s[256];
  const int t = threadIdx.x;
  const int idx = blockIdx.x * 256 + t;
  int val = (idx < N) ? counts[idx] : 0;
  s[t] = val;
  __syncthreads();
  for (int d = 1; d < 256; d <<= 1) {
    int add = (t >= d) ? s[t - d] : 0;
    __syncthreads();
    s[t] += add;
    __syncthreads();
  }
  if (idx < N) excl[idx] = s[t] - val;
  if (t == 255) bsum[blockIdx.x] = s[255];
}

// parallel exclusive scan of the block sums (B <= 1024 fast path)
__global__ __launch_bounds__(1024) void k_scan2(int* __restrict__ bsum, int B) {
  __shared__ int sm[1024];
  const int t = threadIdx.x;
  if (B <= 1024) {
    int val = (t < B) ? bsum[t] : 0;
    sm[t] = val;
    __syncthreads();
    for (int d = 1; d < 1024; d <<= 1) {
      int add = (t >= d) ? sm[t - d] : 0;
      __syncthreads();
      sm[t] += add;
      __syncthreads();
    }
    if (t < B) bsum[t] = sm[t] - val;  // exclusive
  } else if (t == 0) {
    int acc = 0;
    for (int i = 0; i < B; ++i) { int tt = bsum[i]; bsum[i] = acc; acc += tt; }
  }
}

__global__ __launch_bounds__(256) void k_scan3(const int* __restrict__ bsum, int* __restrict__ rowptr,
                                               int* __restrict__ next, int N, int E) {
  int i = blockIdx.x * 256 + threadIdx.x;
  if (i < N) {
    int r = rowptr[i] + bsum[i >> 8];
    rowptr[i] = r;
    next[i] = r;
  }
  if (i == 0) rowptr[N] = E;
}

__global__ __launch_bounds__(256) void k_fill(const int* __restrict__ ei,
                                              const float* __restrict__ node_time,
                                              const float* __restrict__ edge_time,
                                              int* __restrict__ next, int2* __restrict__ er, int E) {
  int e = blockIdx.x * 256 + threadIdx.x;
  if (e < E) {
    int s = ei[e], d = ei[E + e];
    int pos = atomicAdd(&next[d], 1);
    er[pos] = make_int2(s, __float_as_int(node_time[s] - edge_time[e]));
  }
}

// ---------------- K2: CSR gather + online softmax aggregate ----------------
// PERSISTENT grid (768 blocks = ~3072 waves): each wave loops ~33 strided nodes so
// per-wave work concentrates (CLT) and round-stragglers vanish.
__global__ __launch_bounds__(256) void k_aggregate(
    const int* __restrict__ rowptr, const int2* __restrict__ er,
    const float* __restrict__ q, const __half2* __restrict__ kvp,
    const float* __restrict__ time_w, const float* __restrict__ time_b,
    const float* __restrict__ We,
    float* __restrict__ h1, int N) {
  __shared__ float swS[4][64];
  const int tid = threadIdx.x;
  const int c = tid & 63;
  const int wv = tid >> 6;
  const float INV2PI = 0.15915494309189535f;
  float wcol[32], Gw[32];
#pragma unroll
  for (int j = 0; j < 32; ++j) wcol[j] = We[j * 64 + c];
#pragma unroll
  for (int j = 0; j < 32; ++j) Gw[j] = We[(c & 31) * 64 + (c & 32) + j];
  const float tw = time_w[c & 31] * INV2PI;
  const float tb = time_b[c & 31] * INV2PI;
  const int h32 = c & 32;
  const int n0 = blockIdx.x * 4 + wv;
  const int nstride = gridDim.x * 4;
  for (int n = n0; n < N; n += nstride) {
    const int start = rowptr[n];
    const int end = rowptr[n + 1];
    const float qc = q[(size_t)n * 64 + c];  // pre-scaled by 1/sqrt(32)
    // G[c] = sum_j q_s[n, h32+j] * We[c&31, h32+j]  (broadcast LDS reads)
    swS[wv][c] = qc;
    float Gc = 0.f;
#pragma unroll
    for (int j = 0; j < 32; ++j) Gc = fmaf(swS[wv][h32 | j], Gw[j], Gc);
    float m = -1e30f, den = 0.f, num = 0.f, S = 0.f;
    // depth-3 pipeline over packed kv gathers
    float r0 = 0.f, r1 = 0.f, r2 = 0.f;
    __half2 kv0 = __half2(), kv1 = __half2(), kv2 = __half2();
    if (start < end) {
      const int e1 = (start + 1 < end) ? start + 1 : end - 1;
      const int e2 = (start + 2 < end) ? start + 2 : end - 1;
      const int2 a = er[start], b = er[e1], d = er[e2];
      r0 = __int_as_float(a.y); r1 = __int_as_float(b.y); r2 = __int_as_float(d.y);
      kv0 = kvp[(size_t)a.x * 64 + c];
      kv1 = kvp[(size_t)b.x * 64 + c];
      kv2 = kvp[(size_t)d.x * 64 + c];
    }
    for (int e = start; e < end; ++e) {
      // compute edge e (slot0)
      const float kf = __half2float(kv0.x);
      const float vf = __half2float(kv0.y);
      float ang = fmaf(r0, tw, tb);
      ang = ang - floorf(ang);
      const float rv = __builtin_amdgcn_cosf(ang);   // cos(2*pi*ang)
      float p = fmaf(rv, Gc, qc * kf);
#pragma unroll
      for (int msk = 16; msk >= 1; msk >>= 1) p += __shfl_xor(p, msk, 64);
      const float mn = fmaxf(m, p);
      const float sc = __expf(m - mn);
      const float ea = __expf(p - mn);
      num = fmaf(num, sc, ea * vf);
      S   = fmaf(S, sc, ea * rv);
      den = fmaf(den, sc, ea);
      m = mn;
      // rotate + prefetch edge e+3 (wave-uniform branch)
      r0 = r1; kv0 = kv1;
      r1 = r2; kv1 = kv2;
      if (e + 3 < end) {
        const int2 nx = er[e + 3];
        r2 = __int_as_float(nx.y);
        kv2 = kvp[(size_t)nx.x * 64 + c];
      }
    }
    // e-projection contribution: econ[c] = sum_j We[j,c] * S[h32 + j]
    swS[wv][c] = S;
    float econ = 0.f;
#pragma unroll
    for (int j = 0; j < 32; ++j) econ = fmaf(swS[wv][h32 | j], wcol[j], econ);
    const float agg = (num + econ) / (den + 1e-16f);
    h1[(size_t)n * 64 + c] = agg + h1[(size_t)n * 64 + c];  // + staged skip
  }
}

// ---------------- K4: epilogue (context attention + combine + out + log_softmax) ----------------
__global__ __launch_bounds__(256) void k_epilogue(
    const float* __restrict__ t_int, const float* __restrict__ deg,
    const float* __restrict__ cbuf,
    const float* __restrict__ wx_w, const float* __restrict__ wx_b,
    const float* __restrict__ comb_w, const float* __restrict__ comb_b,
    const float* __restrict__ out_w, const float* __restrict__ out_b,
    const int* __restrict__ y, const unsigned char* __restrict__ maskb,
    float* __restrict__ out, int N) {
  __shared__ float sh[4][64];
  const int tid = threadIdx.x;
  const int c = tid & 63;
  const int wv = tid >> 6;
  float wxreg[64], cbreg[64];
#pragma unroll
  for (int j = 0; j < 64; ++j) { wxreg[j] = wx_w[j * 64 + c]; cbreg[j] = comb_w[j * 64 + c]; }
  const float A0 = cbuf[c], B0 = cbuf[64 + c], A1 = cbuf[128 + c], B1 = cbuf[192 + c];
  const float P0 = cbuf[256 + c], Q0 = cbuf[320 + c], P1 = cbuf[384 + c], Q1 = cbuf[448 + c];
  const float wxb = wx_b[c], cbb = comb_b[c];
  const float ow0 = out_w[c * 2 + 0], ow1 = out_w[c * 2 + 1];
  const float ob0 = out_b[0], ob1 = out_b[1];
  const size_t O1 = (size_t)N * 64;
  const size_t O2 = O1 + (size_t)N * 2;
  const size_t O3 = O2 + (size_t)N;
  const int ngroups = (N + 3) >> 2;
  for (int g = blockIdx.x; g < ngroups; g += gridDim.x) {
    const int n = g * 4 + wv;
    const bool act = n < N;
    float h1a = 0.f, ti = 0.f, dg = 0.f;
    if (act) {
      h1a = out[(size_t)n * 64 + c];  // agg + skip, staged by k_aggregate
      ti = t_int[n];
      dg = deg[n];
    }
    sh[wv][c] = h1a;
    __syncthreads();
    const float4* hr = (const float4*)&sh[wv][0];
    float xp = wxb;
    float acc = cbb;
#pragma unroll
    for (int j4 = 0; j4 < 16; ++j4) {
      float4 hv = hr[j4];
      xp  = fmaf(hv.x, wxreg[4 * j4 + 0], xp);
      xp  = fmaf(hv.y, wxreg[4 * j4 + 1], xp);
      xp  = fmaf(hv.z, wxreg[4 * j4 + 2], xp);
      xp  = fmaf(hv.w, wxreg[4 * j4 + 3], xp);
      acc = fmaf(hv.x, cbreg[4 * j4 + 0], acc);
      acc = fmaf(hv.y, cbreg[4 * j4 + 1], acc);
      acc = fmaf(hv.z, cbreg[4 * j4 + 2], acc);
      acc = fmaf(hv.w, cbreg[4 * j4 + 3], acc);
    }
    xp = tanhf(xp);
    const float ep0 = tanhf(fmaf(ti, A0, B0));
    const float ep1 = tanhf(fmaf(dg, A1, B1));
    float d0 = ep0 * xp, d1 = ep1 * xp;
#pragma unroll
    for (int msk = 32; msk >= 1; msk >>= 1) { d0 += __shfl_xor(d0, msk, 64); d1 += __shfl_xor(d1, msk, 64); }
    const float mx = fmaxf(d0, d1);
    const float e0 = expf(d0 - mx), e1 = expf(d1 - mx);
    const float sden = e0 + e1;
    const float s0 = e0 / sden, s1 = e1 / sden;
    acc = fmaf(s0, fmaf(ti, P0, Q0), acc);
    acc = fmaf(s1, fmaf(dg, P1, Q1), acc);
    float z0 = acc * ow0, z1 = acc * ow1;
#pragma unroll
    for (int msk = 32; msk >= 1; msk >>= 1) { z0 += __shfl_xor(z0, msk, 64); z1 += __shfl_xor(z1, msk, 64); }
    if (act) {
      out[(size_t)n * 64 + c] = acc;  // final h1
      if (c == 0) {
        z0 += ob0; z1 += ob1;
        const float mz = fmaxf(z0, z1);
        const float lse = mz + logf(expf(z0 - mz) + expf(z1 - mz));
        out[O1 + (size_t)n * 2 + 0] = z0 - lse;
        out[O1 + (size_t)n * 2 + 1] = z1 - lse;
        out[O2 + (size_t)n] = (float)y[n];
        out[O3 + (size_t)n] = mask_val(maskb, n);
      }
    }
    __syncthreads();
  }
}

extern "C" void kernel_launch(void* const* d_in, const int* in_sizes, int n_in,
                              void* d_out, int out_size, void* d_ws, size_t ws_size,
                              hipStream_t stream) {
  const float* x          = (const float*)d_in[0];
  const int*   ei         = (const int*)d_in[1];
  const float* node_time  = (const float*)d_in[2];
  const float* edge_time  = (const float*)d_in[3];
  const float* nmoti      = (const float*)d_in[4];
  const float* nod        = (const float*)d_in[5];
  const int*   y          = (const int*)d_in[6];
  const unsigned char* mask = (const unsigned char*)d_in[7];
  const float* time_w = (const float*)d_in[8];
  const float* time_b = (const float*)d_in[9];
  const float* tf_w   = (const float*)d_in[10];
  const float* tf_b   = (const float*)d_in[11];
  const float* deg_w  = (const float*)d_in[12];
  const float* deg_b  = (const float*)d_in[13];
  const float* lin_w  = (const float*)d_in[14];
  const float* lin_b  = (const float*)d_in[15];
  const float* Wq     = (const float*)d_in[16];
  const float* bq     = (const float*)d_in[17];
  const float* Wk     = (const float*)d_in[18];
  const float* bk     = (const float*)d_in[19];
  const float* Wv     = (const float*)d_in[20];
  const float* bv     = (const float*)d_in[21];
  const float* We     = (const float*)d_in[22];
  const float* be     = (const float*)d_in[23];
  const float* Wsk    = (const float*)d_in[24];
  const float* bsk    = (const float*)d_in[25];
  const float* wenc_w = (const float*)d_in[26];
  const float* wenc_b = (const float*)d_in[27];
  const float* wx_w   = (const float*)d_in[28];
  const float* wx_b   = (const float*)d_in[29];
  const float* comb_w = (const float*)d_in[30];
  const float* comb_b = (const float*)d_in[31];
  const float* out_w  = (const float*)d_in[32];
  const float* out_b  = (const float*)d_in[33];

  const int N = in_sizes[2];   // node_time
  const int E = in_sizes[3];   // edge_time
  const size_t N64 = (size_t)N * 64;

  float*   q    = (float*)d_ws;
  __half2* kvp  = (__half2*)(q + N64);       // N64 half2 = N64 * 4B
  int2*    er   = (int2*)((char*)kvp + N64 * sizeof(__half2));
  int*     counts = (int*)(er + E);
  int*     rowptr = counts + N;              // N+1 ints
  int*     next   = rowptr + N + 1;
  int*     bsum   = next + N;                // ceil(N/256) ints (padded)
  float*   cbuf   = (float*)(bsum + 4096);
  float*   outf   = (float*)d_out;
  float*   skip   = outf;  // stage skip in d_out[0:N*64)

  const int B = (N + 255) / 256;

  hipMemsetAsync(counts, 0, (size_t)N * sizeof(int), stream);

  k_precompute<<<1, 64, 0, stream>>>(tf_w, tf_b, deg_w, deg_b, wenc_w, wenc_b, comb_w, cbuf);

  const int ntiles = (N + 63) >> 6;
  k_node_proj<<<ntiles, 256, 0, stream>>>(x, lin_w, lin_b, Wq, bq, Wk, bk, Wv, bv, Wsk, bsk,
                                          be, q, kvp, skip, N);

  const int EB = (E + 255) / 256;
  k_hist<<<EB, 256, 0, stream>>>(ei, counts, E);
  k_scan1<<<B, 256, 0, stream>>>(counts, rowptr, bsum, N);
  k_scan2<<<1, 1024, 0, stream>>>(bsum, B);
  k_scan3<<<B, 256, 0, stream>>>(bsum, rowptr, next, N, E);
  k_fill<<<EB, 256, 0, stream>>>(ei, node_time, edge_time, next, er, E);

  // persistent grid: ~3072 waves (matches measured residency), ~33 nodes/wave
  int agb = 768;
  if (agb > (N + 3) / 4) agb = (N + 3) / 4;
  k_aggregate<<<agb, 256, 0, stream>>>(rowptr, er, q, kvp, time_w, time_b, We, outf, N);

  k_epilogue<<<2048, 256, 0, stream>>>(nmoti, nod, cbuf, wx_w, wx_b,
                                       comb_w, comb_b, out_w, out_b, y, mask, outf, N);
}

// Round 8
// 577.289 us; speedup vs baseline: 1.4306x; 1.2089x over previous
//
#include <hip/hip_runtime.h>
#include <hip/hip_fp16.h>

#define DEV __device__ __forceinline__

DEV float mask_val(const unsigned char* mb, int n) {
  // Detect train_mask storage from its first element: uint8 bool / int32 / float32.
  unsigned b0 = mb[0], b1 = mb[1], b2 = mb[2], b3 = mb[3];
  if (b0 <= 1u && b1 == b0 && b2 == b0 && b3 == b0) {
    return mb[n] ? 1.f : 0.f;                       // 1-byte bool
  } else if (b1 == 0u && b2 == 0u && b3 == 0u) {
    return ((const int*)mb)[n] ? 1.f : 0.f;         // int32
  } else {
    return (((const float*)mb)[n] != 0.f) ? 1.f : 0.f; // float32
  }
}

// butterfly sum across each 32-lane half (per-head sum; all lanes receive the result)
DEV float head_sum32(float x) {
  x += __int_as_float(__builtin_amdgcn_ds_swizzle(__float_as_int(x), 0x041F));  // xor 1
  x += __int_as_float(__builtin_amdgcn_ds_swizzle(__float_as_int(x), 0x081F));  // xor 2
  x += __int_as_float(__builtin_amdgcn_ds_swizzle(__float_as_int(x), 0x101F));  // xor 4
  x += __int_as_float(__builtin_amdgcn_ds_swizzle(__float_as_int(x), 0x201F));  // xor 8
  x += __int_as_float(__builtin_amdgcn_ds_swizzle(__float_as_int(x), 0x401F));  // xor 16
  return x;
}

// ---------------- K0: rank-1 collapses of the context-attention algebra ----------------
__global__ void k_precompute(const float* __restrict__ tf_w, const float* __restrict__ tf_b,
                             const float* __restrict__ deg_w, const float* __restrict__ deg_b,
                             const float* __restrict__ wenc_w, const float* __restrict__ wenc_b,
                             const float* __restrict__ comb_w, float* __restrict__ cbuf) {
  int c = threadIdx.x;  // 64 threads
  float A0 = 0, B0 = 0, A1 = 0, B1 = 0, P0 = 0, Q0 = 0, P1 = 0, Q1 = 0;
  for (int j = 0; j < 64; ++j) {
    float w  = wenc_w[j * 64 + c];
    float cw = comb_w[(64 + j) * 64 + c];
    float twj = tf_w[j], tbj = tf_b[j], dwj = deg_w[j], dbj = deg_b[j];
    A0 += twj * w;  B0 += tbj * w;
    A1 += dwj * w;  B1 += dbj * w;
    P0 += twj * cw; Q0 += tbj * cw;
    P1 += dwj * cw; Q1 += dbj * cw;
  }
  float wb = wenc_b[c];
  cbuf[c]       = A0; cbuf[64 + c]  = B0 + wb;
  cbuf[128 + c] = A1; cbuf[192 + c] = B1 + wb;
  cbuf[256 + c] = P0; cbuf[320 + c] = Q0;
  cbuf[384 + c] = P1; cbuf[448 + c] = Q1;
}

// ---------------- K1: h = relu(x@lin); q_s, (k,v) packed fp16 (coalesced half2), skip ----------------
// Two rows x two accumulators = 4 independent FMA chains of length 16.
DEV void dot64_x2(const float* __restrict__ rowA, const float* __restrict__ rowB,
                  const float* __restrict__ w, float bias, float& outA, float& outB) {
  const float4* a4 = (const float4*)rowA;
  const float4* b4 = (const float4*)rowB;
  float a0 = bias, a1 = 0.f, b0 = bias, b1 = 0.f;
#pragma unroll
  for (int j = 0; j < 16; j += 2) {
    float4 va0 = a4[j], va1 = a4[j + 1];
    float4 vb0 = b4[j], vb1 = b4[j + 1];
    a0 = fmaf(va0.x, w[4 * j + 0], a0);
    a0 = fmaf(va0.y, w[4 * j + 1], a0);
    a0 = fmaf(va0.z, w[4 * j + 2], a0);
    a0 = fmaf(va0.w, w[4 * j + 3], a0);
    a1 = fmaf(va1.x, w[4 * j + 4], a1);
    a1 = fmaf(va1.y, w[4 * j + 5], a1);
    a1 = fmaf(va1.z, w[4 * j + 6], a1);
    a1 = fmaf(va1.w, w[4 * j + 7], a1);
    b0 = fmaf(vb0.x, w[4 * j + 0], b0);
    b0 = fmaf(vb0.y, w[4 * j + 1], b0);
    b0 = fmaf(vb0.z, w[4 * j + 2], b0);
    b0 = fmaf(vb0.w, w[4 * j + 3], b0);
    b1 = fmaf(vb1.x, w[4 * j + 4], b1);
    b1 = fmaf(vb1.y, w[4 * j + 5], b1);
    b1 = fmaf(vb1.z, w[4 * j + 6], b1);
    b1 = fmaf(vb1.w, w[4 * j + 7], b1);
  }
  outA = a0 + a1;
  outB = b0 + b1;
}

__global__ __launch_bounds__(256) void k_node_proj(
    const float* __restrict__ x,
    const float* __restrict__ lin_w, const float* __restrict__ lin_b,
    const float* __restrict__ Wq, const float* __restrict__ bq,
    const float* __restrict__ Wk, const float* __restrict__ bk,
    const float* __restrict__ Wv, const float* __restrict__ bv,
    const float* __restrict__ Wsk, const float* __restrict__ bsk,
    const float* __restrict__ be,
    float* __restrict__ q, __half2* __restrict__ kvp,
    float* __restrict__ skipout, int N) {
  __shared__ float xs[4096];   // x tile; reused to stage the k column between mm=1 and mm=2
  __shared__ float hs[4096];
  const int tid = threadIdx.x;
  const int c = tid & 63;
  const int rr0 = tid >> 6;
  const float bec = be[c];
  const float invs = 0.17677669529663687f;  // 1/sqrt(32)
  const int ntiles = (N + 63) >> 6;
  for (int tile = blockIdx.x; tile < ntiles; tile += gridDim.x) {
    const int base = tile << 6;
    if (base + 64 <= N) {
      const float4* x4 = (const float4*)x;
      float4* xs4 = (float4*)xs;
      for (int idx = tid; idx < 1024; idx += 256) xs4[idx] = x4[(size_t)base * 16 + idx];
    } else {
      for (int idx = tid; idx < 4096; idx += 256) {
        int n = base + (idx >> 6);
        xs[idx] = (n < N) ? x[(size_t)n * 64 + (idx & 63)] : 0.f;
      }
    }
    __syncthreads();
    {
      float w[64];
#pragma unroll
      for (int j = 0; j < 64; ++j) w[j] = lin_w[j * 64 + c];
      const float bias = lin_b[c];
#pragma unroll 1
      for (int rr = 0; rr < 8; ++rr) {
        const int rA = rr0 + rr * 4, rB = rA + 32;
        float hA, hB;
        dot64_x2(&xs[rA << 6], &xs[rB << 6], w, bias, hA, hB);
        hs[(rA << 6) + c] = fmaxf(hA, 0.f);
        hs[(rB << 6) + c] = fmaxf(hB, 0.f);
      }
    }
    __syncthreads();
    const float* Wm[4] = {Wq, Wk, Wv, Wsk};
    const float* bm[4] = {bq, bk, bv, bsk};
#pragma unroll 1
    for (int mm = 0; mm < 4; ++mm) {
      float w[64];
#pragma unroll
      for (int j = 0; j < 64; ++j) w[j] = Wm[mm][j * 64 + c];
      const float bias = bm[mm][c] + ((mm == 1 || mm == 2) ? bec : 0.f);
#pragma unroll 1
      for (int rr = 0; rr < 8; ++rr) {
        const int rA = rr0 + rr * 4, rB = rA + 32;
        const int nA = base + rA, nB = base + rB;
        float accA, accB;
        dot64_x2(&hs[rA << 6], &hs[rB << 6], w, bias, accA, accB);
        if (mm == 0) {
          if (nA < N) q[(size_t)nA * 64 + c] = accA * invs;
          if (nB < N) q[(size_t)nB * 64 + c] = accB * invs;
        } else if (mm == 1) {
          xs[(rA << 6) + c] = accA;         // stage k (same thread reads it at mm==2)
          xs[(rB << 6) + c] = accB;
        } else if (mm == 2) {
          if (nA < N)
            kvp[(size_t)nA * 64 + c] =
                __halves2half2(__float2half_rn(xs[(rA << 6) + c]), __float2half_rn(accA));
          if (nB < N)
            kvp[(size_t)nB * 64 + c] =
                __halves2half2(__float2half_rn(xs[(rB << 6) + c]), __float2half_rn(accB));
        } else {
          if (nA < N) skipout[(size_t)nA * 64 + c] = accA;
          if (nB < N) skipout[(size_t)nB * 64 + c] = accB;
        }
      }
    }
    __syncthreads();
  }
}

// ---------------- CSR build ----------------
__global__ __launch_bounds__(256) void k_hist(const int* __restrict__ ei, int* __restrict__ counts, int E) {
  int i = blockIdx.x * 256 + threadIdx.x;
  if (i < E) atomicAdd(&counts[ei[E + i]], 1);
}

__global__ __launch_bounds__(256) void k_scan1(const int* __restrict__ counts, int* __restrict__ excl,
                                               int* __restrict__ bsum, int N) {
  __shared__ int s[256];
  const int t = threadIdx.x;
  const int idx = blockIdx.x * 256 + t;
  int val = (idx < N) ? counts[idx] : 0;
  s[t] = val;
  __syncthreads();
  for (int d = 1; d < 256; d <<= 1) {
    int add = (t >= d) ? s[t - d] : 0;
    __syncthreads();
    s[t] += add;
    __syncthreads();
  }
  if (idx < N) excl[idx] = s[t] - val;
  if (t == 255) bsum[blockIdx.x] = s[255];
}

// parallel exclusive scan of the block sums (B <= 1024 fast path)
__global__ __launch_bounds__(1024) void k_scan2(int* __restrict__ bsum, int B) {
  __shared__ int sm[1024];
  const int t = threadIdx.x;
  if (B <= 1024) {
    int val = (t < B) ? bsum[t] : 0;
    sm[t] = val;
    __syncthreads();
    for (int d = 1; d < 1024; d <<= 1) {
      int add = (t >= d) ? sm[t - d] : 0;
      __syncthreads();
      sm[t] += add;
      __syncthreads();
    }
    if (t < B) bsum[t] = sm[t] - val;  // exclusive
  } else if (t == 0) {
    int acc = 0;
    for (int i = 0; i < B; ++i) { int tt = bsum[i]; bsum[i] = acc; acc += tt; }
  }
}

__global__ __launch_bounds__(256) void k_scan3(const int* __restrict__ bsum, int* __restrict__ rowptr,
                                               int* __restrict__ next, int N, int E) {
  int i = blockIdx.x * 256 + threadIdx.x;
  if (i < N) {
    int r = rowptr[i] + bsum[i >> 8];
    rowptr[i] = r;
    next[i] = r;
  }
  if (i == 0) rowptr[N] = E;
}

__global__ __launch_bounds__(256) void k_fill(const int* __restrict__ ei,
                                              const float* __restrict__ node_time,
                                              const float* __restrict__ edge_time,
                                              int* __restrict__ next, int2* __restrict__ er, int E) {
  int e = blockIdx.x * 256 + threadIdx.x;
  if (e < E) {
    int s = ei[e], d = ei[E + e];
    int pos = atomicAdd(&next[d], 1);
    er[pos] = make_int2(s, __float_as_int(node_time[s] - edge_time[e]));
  }
}

// ---------------- K2: CSR gather + batched two-pass online softmax aggregate ----------------
// One wave per node (persistent grid). Per 16-edge chunk: issue all gathers (MLP=16),
// compute 16 INDEPENDENT alpha butterfly-sums (ds_swizzle, chains overlap), fold the
// chunk max ONCE, rescale state ONCE, then 16 independent exp+FMA updates.
__global__ __launch_bounds__(256) void k_aggregate(
    const int* __restrict__ rowptr, const int2* __restrict__ er,
    const float* __restrict__ q, const unsigned* __restrict__ kvu,
    const float* __restrict__ time_w, const float* __restrict__ time_b,
    const float* __restrict__ We,
    float* __restrict__ h1, int N) {
  __shared__ float swS[4][64];
  const int tid = threadIdx.x;
  const int c = tid & 63;
  const int wv = tid >> 6;
  const float INV2PI = 0.15915494309189535f;
  float wcol[32], Gw[32];
#pragma unroll
  for (int j = 0; j < 32; ++j) wcol[j] = We[j * 64 + c];
#pragma unroll
  for (int j = 0; j < 32; ++j) Gw[j] = We[(c & 31) * 64 + (c & 32) + j];
  const float tw = time_w[c & 31] * INV2PI;
  const float tb = time_b[c & 31] * INV2PI;
  const int h32 = c & 32;
  const int n0 = blockIdx.x * 4 + wv;
  const int nstride = gridDim.x * 4;
  for (int n = n0; n < N; n += nstride) {
    const int start = rowptr[n];
    const int end = rowptr[n + 1];
    const float qc = q[(size_t)n * 64 + c];  // pre-scaled by 1/sqrt(32)
    // G[c] = sum_j q_s[n, h32+j] * We[c&31, h32+j]  (broadcast LDS reads, same wave)
    swS[wv][c] = qc;
    float Gc = 0.f;
#pragma unroll
    for (int j = 0; j < 32; ++j) Gc = fmaf(swS[wv][h32 | j], Gw[j], Gc);
    float m = -1e30f, den = 0.f, num = 0.f, S = 0.f;
    for (int ce = start; ce < end; ce += 16) {
      const int cnt = (end - ce < 16) ? (end - ce) : 16;
      // ---- issue phase: 16 uniform er loads + 16 coalesced kv gathers, all in flight ----
      int src_[16];
      float rr_[16];
#pragma unroll
      for (int i = 0; i < 16; ++i) {
        const int ee = ce + ((i < cnt) ? i : cnt - 1);
        const int2 a = er[ee];
        src_[i] = a.x;
        rr_[i] = __int_as_float(a.y);
      }
      unsigned kvr[16];
#pragma unroll
      for (int i = 0; i < 16; ++i) kvr[i] = kvu[(size_t)src_[i] * 64 + c];
      // ---- pass 1: 16 independent partial products + butterfly sums ----
      float rv_[16], p[16];
#pragma unroll
      for (int i = 0; i < 16; ++i) {
        float ang = fmaf(rr_[i], tw, tb);
        ang = ang - floorf(ang);
        rv_[i] = __builtin_amdgcn_cosf(ang);   // cos(2*pi*ang)
        const __half2 h2 = *(const __half2*)&kvr[i];
        p[i] = fmaf(rv_[i], Gc, qc * __half2float(h2.x));
      }
#pragma unroll
      for (int i = 0; i < 16; ++i) p[i] = head_sum32(p[i]);
#pragma unroll
      for (int i = 0; i < 16; ++i)
        if (i >= cnt) p[i] = -1e30f;           // mask padded duplicates
      // ---- fold chunk max, rescale state once ----
      float cm = p[0];
#pragma unroll
      for (int i = 1; i < 16; ++i) cm = fmaxf(cm, p[i]);
      const float mn = fmaxf(m, cm);
      const float sc = __expf(m - mn);
      num *= sc; den *= sc; S *= sc; m = mn;
      // ---- pass 2: 16 independent exp + FMA updates ----
#pragma unroll
      for (int i = 0; i < 16; ++i) {
        if (i < cnt) {
          const float ea = __expf(p[i] - m);
          const __half2 h2 = *(const __half2*)&kvr[i];
          num = fmaf(ea, __half2float(h2.y), num);
          S = fmaf(ea, rv_[i], S);
          den += ea;
        }
      }
    }
    // e-projection contribution: econ[c] = sum_j We[j,c] * S[h32 + j]
    swS[wv][c] = S;
    float econ = 0.f;
#pragma unroll
    for (int j = 0; j < 32; ++j) econ = fmaf(swS[wv][h32 | j], wcol[j], econ);
    const float agg = (num + econ) / (den + 1e-16f);
    h1[(size_t)n * 64 + c] = agg + h1[(size_t)n * 64 + c];  // + staged skip
  }
}

// ---------------- K4: epilogue (context attention + combine + out + log_softmax) ----------------
__global__ __launch_bounds__(256) void k_epilogue(
    const float* __restrict__ t_int, const float* __restrict__ deg,
    const float* __restrict__ cbuf,
    const float* __restrict__ wx_w, const float* __restrict__ wx_b,
    const float* __restrict__ comb_w, const float* __restrict__ comb_b,
    const float* __restrict__ out_w, const float* __restrict__ out_b,
    const int* __restrict__ y, const unsigned char* __restrict__ maskb,
    float* __restrict__ out, int N) {
  __shared__ float sh[4][64];
  const int tid = threadIdx.x;
  const int c = tid & 63;
  const int wv = tid >> 6;
  float wxreg[64], cbreg[64];
#pragma unroll
  for (int j = 0; j < 64; ++j) { wxreg[j] = wx_w[j * 64 + c]; cbreg[j] = comb_w[j * 64 + c]; }
  const float A0 = cbuf[c], B0 = cbuf[64 + c], A1 = cbuf[128 + c], B1 = cbuf[192 + c];
  const float P0 = cbuf[256 + c], Q0 = cbuf[320 + c], P1 = cbuf[384 + c], Q1 = cbuf[448 + c];
  const float wxb = wx_b[c], cbb = comb_b[c];
  const float ow0 = out_w[c * 2 + 0], ow1 = out_w[c * 2 + 1];
  const float ob0 = out_b[0], ob1 = out_b[1];
  const size_t O1 = (size_t)N * 64;
  const size_t O2 = O1 + (size_t)N * 2;
  const size_t O3 = O2 + (size_t)N;
  const int ngroups = (N + 3) >> 2;
  for (int g = blockIdx.x; g < ngroups; g += gridDim.x) {
    const int n = g * 4 + wv;
    const bool act = n < N;
    float h1a = 0.f, ti = 0.f, dg = 0.f;
    if (act) {
      h1a = out[(size_t)n * 64 + c];  // agg + skip, staged by k_aggregate
      ti = t_int[n];
      dg = deg[n];
    }
    sh[wv][c] = h1a;
    __syncthreads();
    const float4* hr = (const float4*)&sh[wv][0];
    float xp = wxb;
    float acc = cbb;
#pragma unroll
    for (int j4 = 0; j4 < 16; ++j4) {
      float4 hv = hr[j4];
      xp  = fmaf(hv.x, wxreg[4 * j4 + 0], xp);
      xp  = fmaf(hv.y, wxreg[4 * j4 + 1], xp);
      xp  = fmaf(hv.z, wxreg[4 * j4 + 2], xp);
      xp  = fmaf(hv.w, wxreg[4 * j4 + 3], xp);
      acc = fmaf(hv.x, cbreg[4 * j4 + 0], acc);
      acc = fmaf(hv.y, cbreg[4 * j4 + 1], acc);
      acc = fmaf(hv.z, cbreg[4 * j4 + 2], acc);
      acc = fmaf(hv.w, cbreg[4 * j4 + 3], acc);
    }
    xp = tanhf(xp);
    const float ep0 = tanhf(fmaf(ti, A0, B0));
    const float ep1 = tanhf(fmaf(dg, A1, B1));
    float d0 = ep0 * xp, d1 = ep1 * xp;
#pragma unroll
    for (int msk = 32; msk >= 1; msk >>= 1) { d0 += __shfl_xor(d0, msk, 64); d1 += __shfl_xor(d1, msk, 64); }
    const float mx = fmaxf(d0, d1);
    const float e0 = expf(d0 - mx), e1 = expf(d1 - mx);
    const float sden = e0 + e1;
    const float s0 = e0 / sden, s1 = e1 / sden;
    acc = fmaf(s0, fmaf(ti, P0, Q0), acc);
    acc = fmaf(s1, fmaf(dg, P1, Q1), acc);
    float z0 = acc * ow0, z1 = acc * ow1;
#pragma unroll
    for (int msk = 32; msk >= 1; msk >>= 1) { z0 += __shfl_xor(z0, msk, 64); z1 += __shfl_xor(z1, msk, 64); }
    if (act) {
      out[(size_t)n * 64 + c] = acc;  // final h1
      if (c == 0) {
        z0 += ob0; z1 += ob1;
        const float mz = fmaxf(z0, z1);
        const float lse = mz + logf(expf(z0 - mz) + expf(z1 - mz));
        out[O1 + (size_t)n * 2 + 0] = z0 - lse;
        out[O1 + (size_t)n * 2 + 1] = z1 - lse;
        out[O2 + (size_t)n] = (float)y[n];
        out[O3 + (size_t)n] = mask_val(maskb, n);
      }
    }
    __syncthreads();
  }
}

extern "C" void kernel_launch(void* const* d_in, const int* in_sizes, int n_in,
                              void* d_out, int out_size, void* d_ws, size_t ws_size,
                              hipStream_t stream) {
  const float* x          = (const float*)d_in[0];
  const int*   ei         = (const int*)d_in[1];
  const float* node_time  = (const float*)d_in[2];
  const float* edge_time  = (const float*)d_in[3];
  const float* nmoti      = (const float*)d_in[4];
  const float* nod        = (const float*)d_in[5];
  const int*   y          = (const int*)d_in[6];
  const unsigned char* mask = (const unsigned char*)d_in[7];
  const float* time_w = (const float*)d_in[8];
  const float* time_b = (const float*)d_in[9];
  const float* tf_w   = (const float*)d_in[10];
  const float* tf_b   = (const float*)d_in[11];
  const float* deg_w  = (const float*)d_in[12];
  const float* deg_b  = (const float*)d_in[13];
  const float* lin_w  = (const float*)d_in[14];
  const float* lin_b  = (const float*)d_in[15];
  const float* Wq     = (const float*)d_in[16];
  const float* bq     = (const float*)d_in[17];
  const float* Wk     = (const float*)d_in[18];
  const float* bk     = (const float*)d_in[19];
  const float* Wv     = (const float*)d_in[20];
  const float* bv     = (const float*)d_in[21];
  const float* We     = (const float*)d_in[22];
  const float* be     = (const float*)d_in[23];
  const float* Wsk    = (const float*)d_in[24];
  const float* bsk    = (const float*)d_in[25];
  const float* wenc_w = (const float*)d_in[26];
  const float* wenc_b = (const float*)d_in[27];
  const float* wx_w   = (const float*)d_in[28];
  const float* wx_b   = (const float*)d_in[29];
  const float* comb_w = (const float*)d_in[30];
  const float* comb_b = (const float*)d_in[31];
  const float* out_w  = (const float*)d_in[32];
  const float* out_b  = (const float*)d_in[33];

  const int N = in_sizes[2];   // node_time
  const int E = in_sizes[3];   // edge_time
  const size_t N64 = (size_t)N * 64;

  float*   q    = (float*)d_ws;
  __half2* kvp  = (__half2*)(q + N64);       // N64 half2 = N64 * 4B
  int2*    er   = (int2*)((char*)kvp + N64 * sizeof(__half2));
  int*     counts = (int*)(er + E);
  int*     rowptr = counts + N;              // N+1 ints
  int*     next   = rowptr + N + 1;
  int*     bsum   = next + N;                // ceil(N/256) ints (padded)
  float*   cbuf   = (float*)(bsum + 4096);
  float*   outf   = (float*)d_out;
  float*   skip   = outf;  // stage skip in d_out[0:N*64)

  const int B = (N + 255) / 256;

  hipMemsetAsync(counts, 0, (size_t)N * sizeof(int), stream);

  k_precompute<<<1, 64, 0, stream>>>(tf_w, tf_b, deg_w, deg_b, wenc_w, wenc_b, comb_w, cbuf);

  const int ntiles = (N + 63) >> 6;
  k_node_proj<<<ntiles, 256, 0, stream>>>(x, lin_w, lin_b, Wq, bq, Wk, bk, Wv, bv, Wsk, bsk,
                                          be, q, kvp, skip, N);

  const int EB = (E + 255) / 256;
  k_hist<<<EB, 256, 0, stream>>>(ei, counts, E);
  k_scan1<<<B, 256, 0, stream>>>(counts, rowptr, bsum, N);
  k_scan2<<<1, 1024, 0, stream>>>(bsum, B);
  k_scan3<<<B, 256, 0, stream>>>(bsum, rowptr, next, N, E);
  k_fill<<<EB, 256, 0, stream>>>(ei, node_time, edge_time, next, er, E);

  // persistent grid: ~3072 waves, ~33 nodes/wave (CLT-balanced)
  int agb = 768;
  if (agb > (N + 3) / 4) agb = (N + 3) / 4;
  k_aggregate<<<agb, 256, 0, stream>>>(rowptr, er, q, (const unsigned*)kvp,
                                       time_w, time_b, We, outf, N);

  k_epilogue<<<2048, 256, 0, stream>>>(nmoti, nod, cbuf, wx_w, wx_b,
                                       comb_w, comb_b, out_w, out_b, y, mask, outf, N);
}

// Round 9
// 414.087 us; speedup vs baseline: 1.9944x; 1.3941x over previous
//
#include <hip/hip_runtime.h>
#include <hip/hip_fp16.h>

#define DEV __device__ __forceinline__

typedef _Float16 f16x8 __attribute__((ext_vector_type(8)));
typedef float f32x4 __attribute__((ext_vector_type(4)));

DEV float mask_val(const unsigned char* mb, int n) {
  // Detect train_mask storage from its first element: uint8 bool / int32 / float32.
  unsigned b0 = mb[0], b1 = mb[1], b2 = mb[2], b3 = mb[3];
  if (b0 <= 1u && b1 == b0 && b2 == b0 && b3 == b0) {
    return mb[n] ? 1.f : 0.f;                       // 1-byte bool
  } else if (b1 == 0u && b2 == 0u && b3 == 0u) {
    return ((const int*)mb)[n] ? 1.f : 0.f;         // int32
  } else {
    return (((const float*)mb)[n] != 0.f) ? 1.f : 0.f; // float32
  }
}

// butterfly sum across each 32-lane half (per-head sum; all lanes receive the result)
DEV float head_sum32(float x) {
  x += __int_as_float(__builtin_amdgcn_ds_swizzle(__float_as_int(x), 0x041F));  // xor 1
  x += __int_as_float(__builtin_amdgcn_ds_swizzle(__float_as_int(x), 0x081F));  // xor 2
  x += __int_as_float(__builtin_amdgcn_ds_swizzle(__float_as_int(x), 0x101F));  // xor 4
  x += __int_as_float(__builtin_amdgcn_ds_swizzle(__float_as_int(x), 0x201F));  // xor 8
  x += __int_as_float(__builtin_amdgcn_ds_swizzle(__float_as_int(x), 0x401F));  // xor 16
  return x;
}

// ---------------- K0: rank-1 collapses of the context-attention algebra ----------------
__global__ void k_precompute(const float* __restrict__ tf_w, const float* __restrict__ tf_b,
                             const float* __restrict__ deg_w, const float* __restrict__ deg_b,
                             const float* __restrict__ wenc_w, const float* __restrict__ wenc_b,
                             const float* __restrict__ comb_w, float* __restrict__ cbuf) {
  int c = threadIdx.x;  // 64 threads
  float A0 = 0, B0 = 0, A1 = 0, B1 = 0, P0 = 0, Q0 = 0, P1 = 0, Q1 = 0;
  for (int j = 0; j < 64; ++j) {
    float w  = wenc_w[j * 64 + c];
    float cw = comb_w[(64 + j) * 64 + c];
    float twj = tf_w[j], tbj = tf_b[j], dwj = deg_w[j], dbj = deg_b[j];
    A0 += twj * w;  B0 += tbj * w;
    A1 += dwj * w;  B1 += dbj * w;
    P0 += twj * cw; Q0 += tbj * cw;
    P1 += dwj * cw; Q1 += dbj * cw;
  }
  float wb = wenc_b[c];
  cbuf[c]       = A0; cbuf[64 + c]  = B0 + wb;
  cbuf[128 + c] = A1; cbuf[192 + c] = B1 + wb;
  cbuf[256 + c] = P0; cbuf[320 + c] = Q0;
  cbuf[384 + c] = P1; cbuf[448 + c] = Q1;
}

// ---------------- K-wcvt: 5 weights fp32 [k][c] -> fp16 transposed wt[stage][c][k] ----------------
__global__ __launch_bounds__(256) void k_wcvt(
    const float* __restrict__ lin_w, const float* __restrict__ Wq,
    const float* __restrict__ Wk, const float* __restrict__ Wv,
    const float* __restrict__ Wsk, _Float16* __restrict__ wt) {
  const float* Ws[5] = {lin_w, Wq, Wk, Wv, Wsk};
  int idx = blockIdx.x * 256 + threadIdx.x;
  if (idx < 5 * 4096) {
    int s = idx >> 12, r = idx & 4095;
    int j = r >> 6, c = r & 63;
    wt[(s << 12) + c * 64 + j] = (_Float16)Ws[s][j * 64 + c];
  }
}

// ---------------- K1: MFMA node projections ----------------
// Per 64-row tile, wave wv owns rows [16wv,16wv+16). A-frag: row=lane&15, k=(lane>>4)*8+j.
// B-frag from wt (pre-transposed): col=lane&15, k contiguous. C/D: col=lane&15, row=(lane>>4)*4+reg
// (m89-verified). h staged in wave-PRIVATE fp16 LDS (72-padded) -> no barriers at all.
__global__ __launch_bounds__(256) void k_node_proj(
    const float* __restrict__ x, const _Float16* __restrict__ wt,
    const float* __restrict__ lin_b, const float* __restrict__ bq,
    const float* __restrict__ bk, const float* __restrict__ bv,
    const float* __restrict__ bsk, const float* __restrict__ be,
    float* __restrict__ q, __half2* __restrict__ kvp,
    float* __restrict__ skipout, int N) {
  __shared__ _Float16 H[4][16 * 72];
  const int tid = threadIdx.x;
  const int lane = tid & 63;
  const int wv = tid >> 6;
  const int mrow = lane & 15;
  const int kgrp = lane >> 4;
  const float invs = 0.17677669529663687f;  // 1/sqrt(32)
  // hoisted per-output-column biases (output col = nt*16 + mrow)
  float b_lin[4], b_q[4], b_k[4], b_v[4], b_sk[4];
#pragma unroll
  for (int nt = 0; nt < 4; ++nt) {
    const int cc = nt * 16 + mrow;
    b_lin[nt] = lin_b[cc];
    b_q[nt] = bq[cc];
    b_k[nt] = bk[cc] + be[cc];
    b_v[nt] = bv[cc] + be[cc];
    b_sk[nt] = bsk[cc];
  }
  _Float16* Hw = H[wv];
  const int ntiles = (N + 63) >> 6;
  for (int tile = blockIdx.x; tile < ntiles; tile += gridDim.x) {
    const int base = tile << 6;
    const int rowA = base + wv * 16 + mrow;
    const int rclamp = (rowA < N) ? rowA : (N - 1);
    // ---- stage 0: h = relu(x@lin + b); A direct from global (fp32->fp16 in regs) ----
    const float* xr = x + (size_t)rclamp * 64 + kgrp * 8;
    const float4 u0 = *(const float4*)xr;
    const float4 u1 = *(const float4*)(xr + 4);
    const float4 u2 = *(const float4*)(xr + 32);
    const float4 u3 = *(const float4*)(xr + 36);
    const f16x8 a0 = {(_Float16)u0.x, (_Float16)u0.y, (_Float16)u0.z, (_Float16)u0.w,
                      (_Float16)u1.x, (_Float16)u1.y, (_Float16)u1.z, (_Float16)u1.w};
    const f16x8 a1 = {(_Float16)u2.x, (_Float16)u2.y, (_Float16)u2.z, (_Float16)u2.w,
                      (_Float16)u3.x, (_Float16)u3.y, (_Float16)u3.z, (_Float16)u3.w};
#pragma unroll
    for (int nt = 0; nt < 4; ++nt) {
      const _Float16* wb0 = wt + (nt * 16 + mrow) * 64 + kgrp * 8;
      const f16x8 B0 = *(const f16x8*)wb0;
      const f16x8 B1 = *(const f16x8*)(wb0 + 32);
      f32x4 C = {0.f, 0.f, 0.f, 0.f};
      C = __builtin_amdgcn_mfma_f32_16x16x32_f16(a0, B0, C, 0, 0, 0);
      C = __builtin_amdgcn_mfma_f32_16x16x32_f16(a1, B1, C, 0, 0, 0);
#pragma unroll
      for (int r = 0; r < 4; ++r) {
        const float hval = fmaxf(C[r] + b_lin[nt], 0.f);
        Hw[(kgrp * 4 + r) * 72 + nt * 16 + mrow] = (_Float16)hval;
      }
    }
    // A-frags for stages 1-4 (wave-private rows; DS pipe is in-order per wave)
    const f16x8 ha0 = *(const f16x8*)(Hw + mrow * 72 + kgrp * 8);
    const f16x8 ha1 = *(const f16x8*)(Hw + mrow * 72 + 32 + kgrp * 8);
    const int orow0 = base + wv * 16 + kgrp * 4;  // output row of reg r is orow0 + r
    // ---- stage 1: q = (h@Wq + bq) * invs ----
#pragma unroll
    for (int nt = 0; nt < 4; ++nt) {
      const _Float16* wb0 = wt + 4096 + (nt * 16 + mrow) * 64 + kgrp * 8;
      const f16x8 B0 = *(const f16x8*)wb0;
      const f16x8 B1 = *(const f16x8*)(wb0 + 32);
      f32x4 C = {0.f, 0.f, 0.f, 0.f};
      C = __builtin_amdgcn_mfma_f32_16x16x32_f16(ha0, B0, C, 0, 0, 0);
      C = __builtin_amdgcn_mfma_f32_16x16x32_f16(ha1, B1, C, 0, 0, 0);
#pragma unroll
      for (int r = 0; r < 4; ++r) {
        const int orow = orow0 + r;
        if (orow < N) q[(size_t)orow * 64 + nt * 16 + mrow] = (C[r] + b_q[nt]) * invs;
      }
    }
    // ---- stages 2+3: k' and v' -> packed half2 ----
#pragma unroll
    for (int nt = 0; nt < 4; ++nt) {
      const _Float16* wk0 = wt + 2 * 4096 + (nt * 16 + mrow) * 64 + kgrp * 8;
      const _Float16* wv0 = wt + 3 * 4096 + (nt * 16 + mrow) * 64 + kgrp * 8;
      const f16x8 Bk0 = *(const f16x8*)wk0;
      const f16x8 Bk1 = *(const f16x8*)(wk0 + 32);
      const f16x8 Bv0 = *(const f16x8*)wv0;
      const f16x8 Bv1 = *(const f16x8*)(wv0 + 32);
      f32x4 Ck = {0.f, 0.f, 0.f, 0.f};
      f32x4 Cv = {0.f, 0.f, 0.f, 0.f};
      Ck = __builtin_amdgcn_mfma_f32_16x16x32_f16(ha0, Bk0, Ck, 0, 0, 0);
      Ck = __builtin_amdgcn_mfma_f32_16x16x32_f16(ha1, Bk1, Ck, 0, 0, 0);
      Cv = __builtin_amdgcn_mfma_f32_16x16x32_f16(ha0, Bv0, Cv, 0, 0, 0);
      Cv = __builtin_amdgcn_mfma_f32_16x16x32_f16(ha1, Bv1, Cv, 0, 0, 0);
#pragma unroll
      for (int r = 0; r < 4; ++r) {
        const int orow = orow0 + r;
        if (orow < N)
          kvp[(size_t)orow * 64 + nt * 16 + mrow] =
              __halves2half2(__float2half_rn(Ck[r] + b_k[nt]), __float2half_rn(Cv[r] + b_v[nt]));
      }
    }
    // ---- stage 4: skip ----
#pragma unroll
    for (int nt = 0; nt < 4; ++nt) {
      const _Float16* wb0 = wt + 4 * 4096 + (nt * 16 + mrow) * 64 + kgrp * 8;
      const f16x8 B0 = *(const f16x8*)wb0;
      const f16x8 B1 = *(const f16x8*)(wb0 + 32);
      f32x4 C = {0.f, 0.f, 0.f, 0.f};
      C = __builtin_amdgcn_mfma_f32_16x16x32_f16(ha0, B0, C, 0, 0, 0);
      C = __builtin_amdgcn_mfma_f32_16x16x32_f16(ha1, B1, C, 0, 0, 0);
#pragma unroll
      for (int r = 0; r < 4; ++r) {
        const int orow = orow0 + r;
        if (orow < N) skipout[(size_t)orow * 64 + nt * 16 + mrow] = C[r] + b_sk[nt];
      }
    }
  }
}

// ---------------- CSR build ----------------
__global__ __launch_bounds__(256) void k_hist(const int* __restrict__ ei, int* __restrict__ counts, int E) {
  int i = blockIdx.x * 256 + threadIdx.x;
  if (i < E) atomicAdd(&counts[ei[E + i]], 1);
}

__global__ __launch_bounds__(256) void k_scan1(const int* __restrict__ counts, int* __restrict__ excl,
                                               int* __restrict__ bsum, int N) {
  __shared__ int s[256];
  const int t = threadIdx.x;
  const int idx = blockIdx.x * 256 + t;
  int val = (idx < N) ? counts[idx] : 0;
  s[t] = val;
  __syncthreads();
  for (int d = 1; d < 256; d <<= 1) {
    int add = (t >= d) ? s[t - d] : 0;
    __syncthreads();
    s[t] += add;
    __syncthreads();
  }
  if (idx < N) excl[idx] = s[t] - val;
  if (t == 255) bsum[blockIdx.x] = s[255];
}

// parallel exclusive scan of the block sums (B <= 1024 fast path)
__global__ __launch_bounds__(1024) void k_scan2(int* __restrict__ bsum, int B) {
  __shared__ int sm[1024];
  const int t = threadIdx.x;
  if (B <= 1024) {
    int val = (t < B) ? bsum[t] : 0;
    sm[t] = val;
    __syncthreads();
    for (int d = 1; d < 1024; d <<= 1) {
      int add = (t >= d) ? sm[t - d] : 0;
      __syncthreads();
      sm[t] += add;
      __syncthreads();
    }
    if (t < B) bsum[t] = sm[t] - val;  // exclusive
  } else if (t == 0) {
    int acc = 0;
    for (int i = 0; i < B; ++i) { int tt = bsum[i]; bsum[i] = acc; acc += tt; }
  }
}

__global__ __launch_bounds__(256) void k_scan3(const int* __restrict__ bsum, int* __restrict__ rowptr,
                                               int* __restrict__ next, int N, int E) {
  int i = blockIdx.x * 256 + threadIdx.x;
  if (i < N) {
    int r = rowptr[i] + bsum[i >> 8];
    rowptr[i] = r;
    next[i] = r;
  }
  if (i == 0) rowptr[N] = E;
}

__global__ __launch_bounds__(256) void k_fill(const int* __restrict__ ei,
                                              const float* __restrict__ node_time,
                                              const float* __restrict__ edge_time,
                                              int* __restrict__ next, int2* __restrict__ er, int E) {
  int e = blockIdx.x * 256 + threadIdx.x;
  if (e < E) {
    int s = ei[e], d = ei[E + e];
    int pos = atomicAdd(&next[d], 1);
    er[pos] = make_int2(s, __float_as_int(node_time[s] - edge_time[e]));
  }
}

// ---------------- K2: CSR gather + batched two-pass online softmax aggregate ----------------
__global__ __launch_bounds__(256) void k_aggregate(
    const int* __restrict__ rowptr, const int2* __restrict__ er,
    const float* __restrict__ q, const unsigned* __restrict__ kvu,
    const float* __restrict__ time_w, const float* __restrict__ time_b,
    const float* __restrict__ We,
    float* __restrict__ h1, int N) {
  __shared__ float swS[4][64];
  const int tid = threadIdx.x;
  const int c = tid & 63;
  const int wv = tid >> 6;
  const float INV2PI = 0.15915494309189535f;
  float wcol[32], Gw[32];
#pragma unroll
  for (int j = 0; j < 32; ++j) wcol[j] = We[j * 64 + c];
#pragma unroll
  for (int j = 0; j < 32; ++j) Gw[j] = We[(c & 31) * 64 + (c & 32) + j];
  const float tw = time_w[c & 31] * INV2PI;
  const float tb = time_b[c & 31] * INV2PI;
  const int h32 = c & 32;
  const int n0 = blockIdx.x * 4 + wv;
  const int nstride = gridDim.x * 4;
  for (int n = n0; n < N; n += nstride) {
    const int start = rowptr[n];
    const int end = rowptr[n + 1];
    const float qc = q[(size_t)n * 64 + c];  // pre-scaled by 1/sqrt(32)
    swS[wv][c] = qc;
    float Gc = 0.f;
#pragma unroll
    for (int j = 0; j < 32; ++j) Gc = fmaf(swS[wv][h32 | j], Gw[j], Gc);
    float m = -1e30f, den = 0.f, num = 0.f, S = 0.f;
    for (int ce = start; ce < end; ce += 16) {
      const int cnt = (end - ce < 16) ? (end - ce) : 16;
      int src_[16];
      float rr_[16];
#pragma unroll
      for (int i = 0; i < 16; ++i) {
        const int ee = ce + ((i < cnt) ? i : cnt - 1);
        const int2 a = er[ee];
        src_[i] = a.x;
        rr_[i] = __int_as_float(a.y);
      }
      unsigned kvr[16];
#pragma unroll
      for (int i = 0; i < 16; ++i) kvr[i] = kvu[(size_t)src_[i] * 64 + c];
      float rv_[16], p[16];
#pragma unroll
      for (int i = 0; i < 16; ++i) {
        float ang = fmaf(rr_[i], tw, tb);
        ang = ang - floorf(ang);
        rv_[i] = __builtin_amdgcn_cosf(ang);   // cos(2*pi*ang)
        const __half2 h2 = *(const __half2*)&kvr[i];
        p[i] = fmaf(rv_[i], Gc, qc * __half2float(h2.x));
      }
#pragma unroll
      for (int i = 0; i < 16; ++i) p[i] = head_sum32(p[i]);
#pragma unroll
      for (int i = 0; i < 16; ++i)
        if (i >= cnt) p[i] = -1e30f;           // mask padded duplicates
      float cm = p[0];
#pragma unroll
      for (int i = 1; i < 16; ++i) cm = fmaxf(cm, p[i]);
      const float mn = fmaxf(m, cm);
      const float sc = __expf(m - mn);
      num *= sc; den *= sc; S *= sc; m = mn;
#pragma unroll
      for (int i = 0; i < 16; ++i) {
        if (i < cnt) {
          const float ea = __expf(p[i] - m);
          const __half2 h2 = *(const __half2*)&kvr[i];
          num = fmaf(ea, __half2float(h2.y), num);
          S = fmaf(ea, rv_[i], S);
          den += ea;
        }
      }
    }
    swS[wv][c] = S;
    float econ = 0.f;
#pragma unroll
    for (int j = 0; j < 32; ++j) econ = fmaf(swS[wv][h32 | j], wcol[j], econ);
    const float agg = (num + econ) / (den + 1e-16f);
    h1[(size_t)n * 64 + c] = agg + h1[(size_t)n * 64 + c];  // + staged skip
  }
}

// ---------------- K4: epilogue (context attention + combine + out + log_softmax) ----------------
__global__ __launch_bounds__(256) void k_epilogue(
    const float* __restrict__ t_int, const float* __restrict__ deg,
    const float* __restrict__ cbuf,
    const float* __restrict__ wx_w, const float* __restrict__ wx_b,
    const float* __restrict__ comb_w, const float* __restrict__ comb_b,
    const float* __restrict__ out_w, const float* __restrict__ out_b,
    const int* __restrict__ y, const unsigned char* __restrict__ maskb,
    float* __restrict__ out, int N) {
  __shared__ float sh[4][64];
  const int tid = threadIdx.x;
  const int c = tid & 63;
  const int wv = tid >> 6;
  float wxreg[64], cbreg[64];
#pragma unroll
  for (int j = 0; j < 64; ++j) { wxreg[j] = wx_w[j * 64 + c]; cbreg[j] = comb_w[j * 64 + c]; }
  const float A0 = cbuf[c], B0 = cbuf[64 + c], A1 = cbuf[128 + c], B1 = cbuf[192 + c];
  const float P0 = cbuf[256 + c], Q0 = cbuf[320 + c], P1 = cbuf[384 + c], Q1 = cbuf[448 + c];
  const float wxb = wx_b[c], cbb = comb_b[c];
  const float ow0 = out_w[c * 2 + 0], ow1 = out_w[c * 2 + 1];
  const float ob0 = out_b[0], ob1 = out_b[1];
  const size_t O1 = (size_t)N * 64;
  const size_t O2 = O1 + (size_t)N * 2;
  const size_t O3 = O2 + (size_t)N;
  const int ngroups = (N + 3) >> 2;
  for (int g = blockIdx.x; g < ngroups; g += gridDim.x) {
    const int n = g * 4 + wv;
    const bool act = n < N;
    float h1a = 0.f, ti = 0.f, dg = 0.f;
    if (act) {
      h1a = out[(size_t)n * 64 + c];  // agg + skip, staged by k_aggregate
      ti = t_int[n];
      dg = deg[n];
    }
    sh[wv][c] = h1a;
    __syncthreads();
    const float4* hr = (const float4*)&sh[wv][0];
    float xp = wxb;
    float acc = cbb;
#pragma unroll
    for (int j4 = 0; j4 < 16; ++j4) {
      float4 hv = hr[j4];
      xp  = fmaf(hv.x, wxreg[4 * j4 + 0], xp);
      xp  = fmaf(hv.y, wxreg[4 * j4 + 1], xp);
      xp  = fmaf(hv.z, wxreg[4 * j4 + 2], xp);
      xp  = fmaf(hv.w, wxreg[4 * j4 + 3], xp);
      acc = fmaf(hv.x, cbreg[4 * j4 + 0], acc);
      acc = fmaf(hv.y, cbreg[4 * j4 + 1], acc);
      acc = fmaf(hv.z, cbreg[4 * j4 + 2], acc);
      acc = fmaf(hv.w, cbreg[4 * j4 + 3], acc);
    }
    xp = tanhf(xp);
    const float ep0 = tanhf(fmaf(ti, A0, B0));
    const float ep1 = tanhf(fmaf(dg, A1, B1));
    float d0 = ep0 * xp, d1 = ep1 * xp;
#pragma unroll
    for (int msk = 32; msk >= 1; msk >>= 1) { d0 += __shfl_xor(d0, msk, 64); d1 += __shfl_xor(d1, msk, 64); }
    const float mx = fmaxf(d0, d1);
    const float e0 = expf(d0 - mx), e1 = expf(d1 - mx);
    const float sden = e0 + e1;
    const float s0 = e0 / sden, s1 = e1 / sden;
    acc = fmaf(s0, fmaf(ti, P0, Q0), acc);
    acc = fmaf(s1, fmaf(dg, P1, Q1), acc);
    float z0 = acc * ow0, z1 = acc * ow1;
#pragma unroll
    for (int msk = 32; msk >= 1; msk >>= 1) { z0 += __shfl_xor(z0, msk, 64); z1 += __shfl_xor(z1, msk, 64); }
    if (act) {
      out[(size_t)n * 64 + c] = acc;  // final h1
      if (c == 0) {
        z0 += ob0; z1 += ob1;
        const float mz = fmaxf(z0, z1);
        const float lse = mz + logf(expf(z0 - mz) + expf(z1 - mz));
        out[O1 + (size_t)n * 2 + 0] = z0 - lse;
        out[O1 + (size_t)n * 2 + 1] = z1 - lse;
        out[O2 + (size_t)n] = (float)y[n];
        out[O3 + (size_t)n] = mask_val(maskb, n);
      }
    }
    __syncthreads();
  }
}

extern "C" void kernel_launch(void* const* d_in, const int* in_sizes, int n_in,
                              void* d_out, int out_size, void* d_ws, size_t ws_size,
                              hipStream_t stream) {
  const float* x          = (const float*)d_in[0];
  const int*   ei         = (const int*)d_in[1];
  const float* node_time  = (const float*)d_in[2];
  const float* edge_time  = (const float*)d_in[3];
  const float* nmoti      = (const float*)d_in[4];
  const float* nod        = (const float*)d_in[5];
  const int*   y          = (const int*)d_in[6];
  const unsigned char* mask = (const unsigned char*)d_in[7];
  const float* time_w = (const float*)d_in[8];
  const float* time_b = (const float*)d_in[9];
  const float* tf_w   = (const float*)d_in[10];
  const float* tf_b   = (const float*)d_in[11];
  const float* deg_w  = (const float*)d_in[12];
  const float* deg_b  = (const float*)d_in[13];
  const float* lin_w  = (const float*)d_in[14];
  const float* lin_b  = (const float*)d_in[15];
  const float* Wq     = (const float*)d_in[16];
  const float* bq     = (const float*)d_in[17];
  const float* Wk     = (const float*)d_in[18];
  const float* bk     = (const float*)d_in[19];
  const float* Wv     = (const float*)d_in[20];
  const float* bv     = (const float*)d_in[21];
  const float* We     = (const float*)d_in[22];
  const float* be     = (const float*)d_in[23];
  const float* Wsk    = (const float*)d_in[24];
  const float* bsk    = (const float*)d_in[25];
  const float* wenc_w = (const float*)d_in[26];
  const float* wenc_b = (const float*)d_in[27];
  const float* wx_w   = (const float*)d_in[28];
  const float* wx_b   = (const float*)d_in[29];
  const float* comb_w = (const float*)d_in[30];
  const float* comb_b = (const float*)d_in[31];
  const float* out_w  = (const float*)d_in[32];
  const float* out_b  = (const float*)d_in[33];

  const int N = in_sizes[2];   // node_time
  const int E = in_sizes[3];   // edge_time
  const size_t N64 = (size_t)N * 64;

  float*    q    = (float*)d_ws;
  __half2*  kvp  = (__half2*)(q + N64);       // N64 half2 = N64 * 4B
  int2*     er   = (int2*)((char*)kvp + N64 * sizeof(__half2));
  int*      counts = (int*)(er + E);
  int*      rowptr = counts + N;              // N+1 ints
  int*      next   = rowptr + N + 1;
  int*      bsum   = next + N;                // ceil(N/256) ints (padded)
  float*    cbuf   = (float*)(bsum + 4096);
  _Float16* wt     = (_Float16*)(cbuf + 512); // 5 * 4096 fp16
  float*    outf   = (float*)d_out;
  float*    skip   = outf;  // stage skip in d_out[0:N*64)

  const int B = (N + 255) / 256;

  hipMemsetAsync(counts, 0, (size_t)N * sizeof(int), stream);

  k_precompute<<<1, 64, 0, stream>>>(tf_w, tf_b, deg_w, deg_b, wenc_w, wenc_b, comb_w, cbuf);
  k_wcvt<<<80, 256, 0, stream>>>(lin_w, Wq, Wk, Wv, Wsk, wt);

  const int ntiles = (N + 63) >> 6;
  k_node_proj<<<ntiles, 256, 0, stream>>>(x, wt, lin_b, bq, bk, bv, bsk, be,
                                          q, kvp, skip, N);

  const int EB = (E + 255) / 256;
  k_hist<<<EB, 256, 0, stream>>>(ei, counts, E);
  k_scan1<<<B, 256, 0, stream>>>(counts, rowptr, bsum, N);
  k_scan2<<<1, 1024, 0, stream>>>(bsum, B);
  k_scan3<<<B, 256, 0, stream>>>(bsum, rowptr, next, N, E);
  k_fill<<<EB, 256, 0, stream>>>(ei, node_time, edge_time, next, er, E);

  // persistent grid: ~3072 waves, ~33 nodes/wave (CLT-balanced)
  int agb = 768;
  if (agb > (N + 3) / 4) agb = (N + 3) / 4;
  k_aggregate<<<agb, 256, 0, stream>>>(rowptr, er, q, (const unsigned*)kvp,
                                       time_w, time_b, We, outf, N);

  k_epilogue<<<2048, 256, 0, stream>>>(nmoti, nod, cbuf, wx_w, wx_b,
                                       comb_w, comb_b, out_w, out_b, y, mask, outf, N);
}